// Round 6
// baseline (321.491 us; speedup 1.0000x reference)
//
#include <hip/hip_runtime.h>
#include <math.h>

#define B_  2
#define N_  4096
#define K_  16
#define D_  64
#define CM_ 64
#define H_  8

// ---------------------------------------------------------------- kNN ------
#define NSEG  8
#define SEGSZ (N_ / NSEG)   // 512
#define QPB   256
#define LIM   16

__device__ __forceinline__ void ce64(unsigned long long& a, unsigned long long& b) {
    bool sw = b < a;
    unsigned long long lo = sw ? b : a;
    unsigned long long hi = sw ? a : b;
    a = lo; b = hi;
}

// Batcher odd-even mergesort n=16: straight-line, literal indices (in-register!)
#define SORT16(e) do { \
    ce64(e[0],e[1]); ce64(e[2],e[3]); ce64(e[4],e[5]); ce64(e[6],e[7]); \
    ce64(e[8],e[9]); ce64(e[10],e[11]); ce64(e[12],e[13]); ce64(e[14],e[15]); \
    ce64(e[0],e[2]); ce64(e[1],e[3]); ce64(e[4],e[6]); ce64(e[5],e[7]); \
    ce64(e[8],e[10]); ce64(e[9],e[11]); ce64(e[12],e[14]); ce64(e[13],e[15]); \
    ce64(e[1],e[2]); ce64(e[5],e[6]); ce64(e[9],e[10]); ce64(e[13],e[14]); \
    ce64(e[0],e[4]); ce64(e[1],e[5]); ce64(e[2],e[6]); ce64(e[3],e[7]); \
    ce64(e[8],e[12]); ce64(e[9],e[13]); ce64(e[10],e[14]); ce64(e[11],e[15]); \
    ce64(e[2],e[4]); ce64(e[3],e[5]); ce64(e[10],e[12]); ce64(e[11],e[13]); \
    ce64(e[1],e[2]); ce64(e[3],e[4]); ce64(e[5],e[6]); \
    ce64(e[9],e[10]); ce64(e[11],e[12]); ce64(e[13],e[14]); \
    ce64(e[0],e[8]); ce64(e[1],e[9]); ce64(e[2],e[10]); ce64(e[3],e[11]); \
    ce64(e[4],e[12]); ce64(e[5],e[13]); ce64(e[6],e[14]); ce64(e[7],e[15]); \
    ce64(e[4],e[8]); ce64(e[5],e[9]); ce64(e[6],e[10]); ce64(e[7],e[11]); \
    ce64(e[2],e[4]); ce64(e[3],e[5]); ce64(e[6],e[8]); ce64(e[7],e[9]); \
    ce64(e[10],e[12]); ce64(e[11],e[13]); \
    ce64(e[1],e[2]); ce64(e[3],e[4]); ce64(e[5],e[6]); ce64(e[7],e[8]); \
    ce64(e[9],e[10]); ce64(e[11],e[12]); ce64(e[13],e[14]); \
} while (0)

// bitonic cleanup n=16 (input bitonic, output sorted asc)
#define BMERGE16(d) do { \
    ce64(d[0],d[8]); ce64(d[1],d[9]); ce64(d[2],d[10]); ce64(d[3],d[11]); \
    ce64(d[4],d[12]); ce64(d[5],d[13]); ce64(d[6],d[14]); ce64(d[7],d[15]); \
    ce64(d[0],d[4]); ce64(d[1],d[5]); ce64(d[2],d[6]); ce64(d[3],d[7]); \
    ce64(d[8],d[12]); ce64(d[9],d[13]); ce64(d[10],d[14]); ce64(d[11],d[15]); \
    ce64(d[0],d[2]); ce64(d[1],d[3]); ce64(d[4],d[6]); ce64(d[5],d[7]); \
    ce64(d[8],d[10]); ce64(d[9],d[11]); ce64(d[12],d[14]); ce64(d[13],d[15]); \
    ce64(d[0],d[1]); ce64(d[2],d[3]); ce64(d[4],d[5]); ce64(d[6],d[7]); \
    ce64(d[8],d[9]); ce64(d[10],d[11]); ce64(d[12],d[13]); ce64(d[14],d[15]); \
} while (0)

// spw = segments-per-which handled by this launch; seg = seg_off + z%spw.
// warm: initialize tau from segment-0's 16th-best distance (conservative
// bound: seg0_d16 >= global_d16; the 2^-10 filter slack admits exact ties).
__global__ __launch_bounds__(256) void knn_seg_kernel(
    const float* __restrict__ xyz1, const float* __restrict__ xyz2,
    const float* __restrict__ xyz2w,
    float* __restrict__ segD, int* __restrict__ segI,
    int spw, int seg_off, int warm)
{
    const int b = blockIdx.y;
    const int which = blockIdx.z / spw;
    const int seg   = seg_off + blockIdx.z % spw;
    const float* q = xyz1 + (size_t)b * 3 * N_;
    const float* r = (which == 0 ? xyz2 : (which == 1 ? xyz2w : xyz1)) + (size_t)b * 3 * N_;

    const int tid = threadIdx.x;
    const int qi = blockIdx.x * QPB + tid;
    const float qx = q[qi], qy = q[N_ + qi], qz = q[2 * N_ + qi];
    const float qq = qx * qx + qy * qy + qz * qz;

    __shared__ float4 tile[SEGSZ];       // 8 KB
    __shared__ float  bufD[LIM * QPB];   // 16 KB, column tid -> bank tid%32
    __shared__ int    bufI[LIM * QPB];   // 16 KB

    unsigned long long bd[K_];           // sorted asc (d_bits<<32 | idx)
#pragma unroll
    for (int i = 0; i < K_; ++i) bd[i] = ~0ull;
    float tau = 3.4e38f;
    if (warm)   // warm start: seg0's 16th-best distance for this query
        tau = segD[((((size_t)b * 3 + which) * NSEG + 0) * N_ + qi) * K_ + (K_ - 1)];
    float c = 0.5f * (qq - tau);
    c -= fabsf(c) * 0.0009765625f + 1e-20f;   // slack: filter never rejects d<=tau
    int cnt = 0;

    const int base0 = seg * SEGSZ;
    for (int j = tid; j < SEGSZ; j += QPB) {
        float x = r[base0 + j], y = r[N_ + base0 + j], z = r[2 * N_ + base0 + j];
        tile[j] = make_float4(x, y, z, x * x + y * y + z * z);
    }
    __syncthreads();

    auto compact = [&](int m_end) {
        unsigned long long e[16];
#pragma unroll
        for (int m = 0; m < 16; ++m) {
            float dv = bufD[m * QPB + tid];
            int   iv = bufI[m * QPB + tid];
            unsigned long long key =
                ((unsigned long long)__float_as_uint(dv) << 32) | (unsigned)iv;
            e[m] = (m < m_end) ? key : ~0ull;
        }
        SORT16(e);                                   // sort 16 (in registers)
#pragma unroll
        for (int i = 0; i < 16; ++i) {               // min-halve vs running top-16
            unsigned long long cand = e[15 - i];
            if (cand < bd[i]) bd[i] = cand;
        }
        BMERGE16(bd);                                // bitonic cleanup
        tau = fminf(tau, __uint_as_float((unsigned)(bd[K_ - 1] >> 32)));
        c = 0.5f * (qq - tau);
        c -= fabsf(c) * 0.0009765625f + 1e-20f;
    };

    for (int j = 0; j < SEGSZ; ++j) {
        float4 t = tile[j];
        float dot = qx * t.x + qy * t.y + qz * t.z;
        float s = dot - 0.5f * t.w;
        if (s > c) {                            // cheap conservative filter
            float d = fmaxf((qq + t.w) - 2.0f * dot, 0.0f);   // canonical d
            bufD[cnt * QPB + tid] = d;
            bufI[cnt * QPB + tid] = base0 + j;
            ++cnt;
        }
        if (__any(cnt == LIM)) {                // wave-synchronized batch merge
            compact(cnt);
            cnt = 0;
        }
    }
    if (__any(cnt != 0)) compact(cnt);          // skip if nothing buffered

    const size_t ob = ((((size_t)b * 3 + which) * NSEG + seg) * N_ + qi) * K_;
#pragma unroll
    for (int i = 0; i < K_; ++i) {
        segD[ob + i] = __uint_as_float((unsigned)(bd[i] >> 32));
        segI[ob + i] = (int)(unsigned)bd[i];
    }
}

__global__ __launch_bounds__(256) void knn_merge_kernel(
    const float* __restrict__ segD, const int* __restrict__ segI,
    int* __restrict__ idxA, int* __restrict__ idxB, int* __restrict__ idxS)
{
    const int b = blockIdx.y, which = blockIdx.z;
    const int qi = blockIdx.x * 256 + threadIdx.x;
    unsigned long long m[K_];
#pragma unroll
    for (int i = 0; i < K_; ++i) m[i] = ~0ull;
    for (int s = 0; s < NSEG; ++s) {
        const size_t ob = ((((size_t)b * 3 + which) * NSEG + s) * N_ + qi) * K_;
        for (int e = 0; e < K_; ++e) {
            unsigned long long key =
                ((unsigned long long)__float_as_uint(segD[ob + e]) << 32)
                | (unsigned)segI[ob + e];
            if (key >= m[K_ - 1]) break;        // seg list sorted: rest fail too
            m[K_ - 1] = key;
#pragma unroll
            for (int i = K_ - 1; i > 0; --i) {
                if (m[i] < m[i - 1]) {
                    unsigned long long t = m[i]; m[i] = m[i - 1]; m[i - 1] = t;
                }
            }
        }
    }
    int* outp = (which == 0 ? idxA : (which == 1 ? idxB : idxS));
    int* op = outp + ((size_t)b * N_ + qi) * K_;
#pragma unroll
    for (int i = 0; i < K_; ++i) op[i] = (int)(unsigned)m[i];
}

// ----------------------------------------------------- MLP pre-GEMMs -------
// G1[b][n][o] = sum_c points1[b,c,n] * W0[o][c]        (z=0)
// P2[b][n][o] = sum_c points2[b,c,n] * W0[o][64+c]     (z=1)
__global__ __launch_bounds__(256) void pre_gemm_kernel(
    const float* __restrict__ points1, const float* __restrict__ points2,
    const float* __restrict__ W0,
    float* __restrict__ G1, float* __restrict__ P2)
{
    const int b = blockIdx.y, which = blockIdx.z;
    const float* src = which ? points2 : points1;
    float* dst = which ? P2 : G1;
    const int woff = which ? 64 : 0;
    const int n0 = blockIdx.x * 64;
    const int tid = threadIdx.x;

    __shared__ float sW[64 * 65];   // [c][o]
    __shared__ float sA[64 * 68];   // [c][n] pad 68

    for (int i = tid; i < 4096; i += 256) {
        int c = i & 63, o = i >> 6;
        sW[c * 65 + o] = W0[o * 131 + woff + c];
    }
    for (int i = tid; i < 4096; i += 256) {
        int n = i & 63, c = i >> 6;
        sA[c * 68 + n] = src[((size_t)b * 64 + c) * N_ + n0 + n];
    }
    __syncthreads();

    const int o = tid & 63, qg = tid >> 6;
    float acc[16];
#pragma unroll
    for (int j = 0; j < 16; ++j) acc[j] = 0.f;
    for (int c = 0; c < 64; ++c) {
        float w = sW[c * 65 + o];
        const float4* ap = (const float4*)&sA[c * 68 + qg * 16];
#pragma unroll
        for (int m = 0; m < 4; ++m) {
            float4 a4 = ap[m];
            acc[4 * m + 0] += w * a4.x;
            acc[4 * m + 1] += w * a4.y;
            acc[4 * m + 2] += w * a4.z;
            acc[4 * m + 3] += w * a4.w;
        }
    }
#pragma unroll
    for (int j = 0; j < 16; ++j)
        dst[((size_t)b * N_ + n0 + qg * 16 + j) * 64 + o] = acc[j];
}

// ----------------------------------------------------- MLP main ------------
__global__ __launch_bounds__(256) void mlp2_kernel(
    const float* __restrict__ xyz1, const float* __restrict__ xyz2,
    const float* __restrict__ xyz2w,
    const int* __restrict__ idxA, const int* __restrict__ idxB,
    const float* __restrict__ G1, const float* __restrict__ P2,
    const float* __restrict__ W0, const float* __restrict__ b0,
    const float* __restrict__ W1, const float* __restrict__ b1,
    float* __restrict__ feat, float* __restrict__ featw)
{
    const int b = blockIdx.y, which = blockIdx.z;
    const int* idx = which ? idxB : idxA;
    const float* refxyz = (which ? xyz2w : xyz2) + (size_t)b * 3 * N_;
    float* outp = which ? featw : feat;
    const int n0 = blockIdx.x * 8;
    const int tid = threadIdx.x;
    const int w = tid >> 6, lane = tid & 63;

    __shared__ float sh0[64 * 132];   // [c][row]
    __shared__ float sW1[64 * 68];    // [c][o]
    __shared__ float sWc[3 * 64];
    __shared__ float sB0[64];
    __shared__ float sQ[3][8];
    __shared__ int   sIdx[128];

    for (int i = tid; i < 4096; i += 256) {
        int c = i & 63, o = i >> 6;
        sW1[c * 68 + o] = W1[o * 64 + c];
    }
    if (tid < 192) { int m = tid >> 6, o = tid & 63; sWc[m * 64 + o] = W0[o * 131 + 128 + m]; }
    if (tid < 64) sB0[tid] = b0[tid];
    if (tid < 24) { int m = tid >> 3, j = tid & 7; sQ[m][j] = xyz1[((size_t)b * 3 + m) * N_ + n0 + j]; }
    if (tid < 128) sIdx[tid] = idx[((size_t)b * N_ + n0 + (tid >> 4)) * K_ + (tid & 15)];
    __syncthreads();

    {
        const int o = lane;
        const float wc0 = sWc[o], wc1 = sWc[64 + o], wc2 = sWc[128 + o];
        const float bb0 = sB0[o];
#pragma unroll
        for (int p = 0; p < 2; ++p) {
            const int pl = w * 2 + p;
            const float g1 = G1[((size_t)b * N_ + n0 + pl) * 64 + o];
            const float qx = sQ[0][pl], qy = sQ[1][pl], qz = sQ[2][pl];
            for (int k = 0; k < K_; ++k) {
                const int row = pl * K_ + k;
                const int ii = sIdx[row];
                float p2 = P2[((size_t)b * N_ + ii) * 64 + o];
                float dx = refxyz[ii] - qx;
                float dy = refxyz[N_ + ii] - qy;
                float dz = refxyz[2 * N_ + ii] - qz;
                float h = g1 + p2 + dx * wc0 + dy * wc1 + dz * wc2 + bb0;
                h = h >= 0.f ? h : 0.1f * h;
                sh0[o * 132 + row] = h;
            }
        }
    }
    __syncthreads();

    const int lr = lane >> 3, lo = lane & 7;
    float accv[4][8];
    {
        float4 bva = *(const float4*)&b1[lo * 8];
        float4 bvb = *(const float4*)&b1[lo * 8 + 4];
#pragma unroll
        for (int dr = 0; dr < 4; ++dr) {
            accv[dr][0] = bva.x; accv[dr][1] = bva.y; accv[dr][2] = bva.z; accv[dr][3] = bva.w;
            accv[dr][4] = bvb.x; accv[dr][5] = bvb.y; accv[dr][6] = bvb.z; accv[dr][7] = bvb.w;
        }
    }
    for (int c = 0; c < 64; ++c) {
        float4 a4 = *(const float4*)&sh0[c * 132 + w * 32 + lr * 4];
        float4 wa = *(const float4*)&sW1[c * 68 + lo * 8];
        float4 wb = *(const float4*)&sW1[c * 68 + lo * 8 + 4];
        float av[4] = {a4.x, a4.y, a4.z, a4.w};
        float wv[8] = {wa.x, wa.y, wa.z, wa.w, wb.x, wb.y, wb.z, wb.w};
#pragma unroll
        for (int dr = 0; dr < 4; ++dr)
#pragma unroll
            for (int j = 0; j < 8; ++j)
                accv[dr][j] += av[dr] * wv[j];
    }
#pragma unroll
    for (int dr = 0; dr < 4; ++dr) {
        const int row = w * 32 + lr * 4 + dr;
        const int pl = row >> 4, k = row & 15;
        float o8[8];
#pragma unroll
        for (int j = 0; j < 8; ++j) {
            float v = accv[dr][j];
            o8[j] = v >= 0.f ? v : 0.1f * v;
        }
        float* op = outp + (((size_t)b * N_ + n0 + pl) * K_ + k) * 64 + lo * 8;
        *(float4*)op = make_float4(o8[0], o8[1], o8[2], o8[3]);
        *(float4*)(op + 4) = make_float4(o8[4], o8[5], o8[6], o8[7]);
    }
}

// --------------------------------------------------------------- attn ------
#define NCHUNK 32
#define CG 16

__global__ __launch_bounds__(256) void attn_partial_kernel(
    const float* __restrict__ feat, const float* __restrict__ featw,
    float* __restrict__ partial)
{
    const int chunk = blockIdx.x;
    const int b = blockIdx.y >> 2;
    const int c0 = (blockIdx.y & 3) * CG;
    const int tid = threadIdx.x;
    const int k = tid >> 4, c = tid & 15;

    __shared__ float sf[16 * 16 * 17];
    __shared__ float sfw[16 * 16 * 20];

    float acc[K_];
#pragma unroll
    for (int l = 0; l < K_; ++l) acc[l] = 0.f;

    const int n0 = chunk * (N_ / NCHUNK);
    for (int ns = 0; ns < N_ / NCHUNK; ns += 16) {
        __syncthreads();
        for (int i = tid; i < 4096; i += 256) {
            int nn = i >> 8, p = (i >> 4) & 15, qv = i & 15;
            size_t base = (((size_t)b * N_ + n0 + ns + nn) * K_ + p) * CM_ + c0 + qv;
            sf[nn * 272 + p * 17 + qv]  = feat[base];
            sfw[nn * 320 + qv * 20 + p] = featw[base];
        }
        __syncthreads();
#pragma unroll
        for (int nn = 0; nn < 16; ++nn) {
            float f = sf[nn * 272 + k * 17 + c];
            const float4* fp = (const float4*)&sfw[nn * 320 + c * 20];
#pragma unroll
            for (int m = 0; m < 4; ++m) {
                float4 v = fp[m];
                acc[4 * m + 0] += f * v.x;
                acc[4 * m + 1] += f * v.y;
                acc[4 * m + 2] += f * v.z;
                acc[4 * m + 3] += f * v.w;
            }
        }
    }
    float* pp = partial + ((((size_t)b * NCHUNK + chunk) * CM_ + (c0 + c)) * K_ + k) * K_;
#pragma unroll
    for (int m = 0; m < 4; ++m)
        *(float4*)(pp + 4 * m) = make_float4(acc[4 * m], acc[4 * m + 1], acc[4 * m + 2], acc[4 * m + 3]);
}

__global__ __launch_bounds__(256) void attn_reduce_kernel(
    const float* __restrict__ partial,
    float* __restrict__ rowsum, float* __restrict__ colsum)
{
    const int c = blockIdx.x, b = blockIdx.y;
    const int tid = threadIdx.x;
    const int k = tid >> 4, l = tid & 15;
    __shared__ float smat[K_][K_ + 1];

    float acc = 0.f;
#pragma unroll
    for (int ch = 0; ch < NCHUNK; ++ch)
        acc += partial[((((size_t)b * NCHUNK + ch) * CM_ + c) * K_ + k) * K_ + l];

    float m = acc;
#pragma unroll
    for (int off = 8; off >= 1; off >>= 1) m = fmaxf(m, __shfl_xor(m, off, 16));
    float e = expf(acc - m);
    float s = e;
#pragma unroll
    for (int off = 8; off >= 1; off >>= 1) s += __shfl_xor(s, off, 16);
    float sm = fmaxf((e / s) * 0.57735026918962576f, 1e-10f);

    float rs = sm;
#pragma unroll
    for (int off = 8; off >= 1; off >>= 1) rs += __shfl_xor(rs, off, 16);
    if (l == 0) rowsum[((size_t)b * CM_ + c) * K_ + k] = rs;

    smat[k][l] = sm;
    __syncthreads();
    if (tid < K_) {
        float cs = 0.f;
#pragma unroll
        for (int kk = 0; kk < K_; ++kk) cs += smat[kk][tid];
        colsum[((size_t)b * CM_ + c) * K_ + tid] = cs;
    }
}

// --------------------------------------------------------------- cost ------
__global__ __launch_bounds__(256) void cost_kernel(
    const float* __restrict__ feat, const float* __restrict__ featw,
    const float* __restrict__ rowsum, const float* __restrict__ colsum,
    float* __restrict__ costT, float* __restrict__ costwT)
{
    const int b = blockIdx.y;
    const int tid = threadIdx.x;
    __shared__ float scs[64][K_ + 1], srs[64][K_ + 1];
    for (int i = tid; i < 64 * K_; i += 256) {
        int cc = i >> 4, j = i & 15;
        scs[cc][j] = colsum[((size_t)b * CM_ + cc) * K_ + j];
        srs[cc][j] = rowsum[((size_t)b * CM_ + cc) * K_ + j];
    }
    __syncthreads();
    const int ng = tid >> 6, c = tid & 63;
    const int n = blockIdx.x * 4 + ng;
    const float* fp  = feat  + (((size_t)b * N_ + n) * K_) * 64 + c;
    const float* fwp = featw + (((size_t)b * N_ + n) * K_) * 64 + c;
    float a = 0.f, aw = 0.f;
#pragma unroll
    for (int j = 0; j < K_; ++j) {
        a  += fp[j * 64]  * scs[c][j];
        aw += fwp[j * 64] * srs[c][j];
    }
    costT[((size_t)b * N_ + n) * 64 + c]  = a;
    costwT[((size_t)b * N_ + n) * 64 + c] = aw;
}

// -------------------------------------------------------------- final ------
__global__ __launch_bounds__(256) void final_kernel(
    const float* __restrict__ xyz1,
    const int* __restrict__ idxS,
    const float* __restrict__ costT, const float* __restrict__ costwT,
    const float* __restrict__ wn_W0, const float* __restrict__ wn_b0,
    const float* __restrict__ wn_g0, const float* __restrict__ wn_be0,
    const float* __restrict__ wn_W1, const float* __restrict__ wn_b1,
    const float* __restrict__ wn_g1, const float* __restrict__ wn_be1,
    const float* __restrict__ wn_W2, const float* __restrict__ wn_b2,
    const float* __restrict__ wn_g2, const float* __restrict__ wn_be2,
    float* __restrict__ out)
{
    const int b = blockIdx.y;
    const int tid = threadIdx.x;
    const int ng = tid >> 6, c = tid & 63;
    const int n = blockIdx.x * 4 + ng;
    const float invs = 1.0f / sqrtf(1.0f + 1e-5f);

    __shared__ int   sI[4][K_];
    __shared__ float sH1[4][K_][H_];

    if (c < K_) {
        const int k = c;
        const float* qb = xyz1 + (size_t)b * 3 * N_;
        int ii = idxS[((size_t)b * N_ + n) * K_ + k];
        sI[ng][k] = ii;
        float dx = qb[ii] - qb[n];
        float dy = qb[N_ + ii] - qb[N_ + n];
        float dz = qb[2 * N_ + ii] - qb[2 * N_ + n];
        float h0[H_];
#pragma unroll
        for (int o = 0; o < H_; ++o) {
            float v = wn_W0[o * 3] * dx + wn_W0[o * 3 + 1] * dy + wn_W0[o * 3 + 2] * dz + wn_b0[o];
            v = v * (wn_g0[o] * invs) + wn_be0[o];
            h0[o] = fmaxf(v, 0.f);
        }
#pragma unroll
        for (int o = 0; o < H_; ++o) {
            float v = wn_b1[o];
#pragma unroll
            for (int j = 0; j < H_; ++j) v += wn_W1[o * H_ + j] * h0[j];
            v = v * (wn_g1[o] * invs) + wn_be1[o];
            sH1[ng][k][o] = fmaxf(v, 0.f);
        }
    }
    __syncthreads();

    float w2r[H_];
#pragma unroll
    for (int j = 0; j < H_; ++j) w2r[j] = wn_W2[c * H_ + j];
    const float b2v = wn_b2[c];
    const float s2v = wn_g2[c] * invs;
    const float t2v = wn_be2[c];

    float acc = 0.f;
#pragma unroll
    for (int k = 0; k < K_; ++k) {
        float v = b2v;
#pragma unroll
        for (int j = 0; j < H_; ++j) v += w2r[j] * sH1[ng][k][j];
        float wv = fmaxf(v * s2v + t2v, 0.f);
        int ii = sI[ng][k];
        size_t base = ((size_t)b * N_ + ii) * 64 + c;
        acc += wv * (costT[base] + costwT[base]);
    }
    out[((size_t)b * CM_ + c) * N_ + n] = acc;
}

// ------------------------------------------------------------- launch ------
extern "C" void kernel_launch(void* const* d_in, const int* in_sizes, int n_in,
                              void* d_out, int out_size, void* d_ws, size_t ws_size,
                              hipStream_t stream)
{
    const float* xyz1    = (const float*)d_in[0];
    const float* xyz2    = (const float*)d_in[1];
    const float* xyz2w   = (const float*)d_in[2];
    const float* points1 = (const float*)d_in[3];
    const float* points2 = (const float*)d_in[4];
    const float* mlp_W0  = (const float*)d_in[5];
    const float* mlp_b0  = (const float*)d_in[6];
    const float* mlp_W1  = (const float*)d_in[7];
    const float* mlp_b1  = (const float*)d_in[8];
    const float* wn_W0   = (const float*)d_in[9];
    const float* wn_b0   = (const float*)d_in[10];
    const float* wn_g0   = (const float*)d_in[11];
    const float* wn_be0  = (const float*)d_in[12];
    const float* wn_W1   = (const float*)d_in[13];
    const float* wn_b1   = (const float*)d_in[14];
    const float* wn_g1   = (const float*)d_in[15];
    const float* wn_be1  = (const float*)d_in[16];
    const float* wn_W2   = (const float*)d_in[17];
    const float* wn_b2   = (const float*)d_in[18];
    const float* wn_g2   = (const float*)d_in[19];
    const float* wn_be2  = (const float*)d_in[20];
    float* out = (float*)d_out;

    char* ws = (char*)d_ws;
    size_t off = 0;
    auto alloc = [&](size_t bytes) -> void* {
        void* p = ws + off;
        off += (bytes + 255) & ~(size_t)255;
        return p;
    };
    int*   idxA   = (int*)  alloc((size_t)B_ * N_ * K_ * sizeof(int));
    int*   idxB   = (int*)  alloc((size_t)B_ * N_ * K_ * sizeof(int));
    int*   idxS   = (int*)  alloc((size_t)B_ * N_ * K_ * sizeof(int));
    float* feat   = (float*)alloc((size_t)B_ * N_ * K_ * CM_ * sizeof(float));
    float* featw  = (float*)alloc((size_t)B_ * N_ * K_ * CM_ * sizeof(float));
    float* rowsum = (float*)alloc((size_t)B_ * CM_ * K_ * sizeof(float));
    float* colsum = (float*)alloc((size_t)B_ * CM_ * K_ * sizeof(float));
    float* costT  = (float*)alloc((size_t)B_ * N_ * CM_ * sizeof(float));
    float* costwT = (float*)alloc((size_t)B_ * N_ * CM_ * sizeof(float));
    (void)ws_size; (void)in_sizes; (void)n_in; (void)out_size;

    // Aliases, lifetimes chained by stream order (see earlier rounds).
    float* segD    = feat;
    int*   segI    = (int*)featw;
    float* G1      = costT;
    float* P2      = costwT;
    float* partial = costT;

    pre_gemm_kernel<<<dim3(N_ / 64, B_, 2), 256, 0, stream>>>(points1, points2, mlp_W0, G1, P2);
    // phase 1: segment 0, cold start (computes per-query tau = seg0 d16)
    knn_seg_kernel<<<dim3(N_ / QPB, B_, 3), QPB, 0, stream>>>(
        xyz1, xyz2, xyz2w, segD, segI, /*spw=*/1, /*seg_off=*/0, /*warm=*/0);
    // phase 2: segments 1..7, warm-started from seg0's tau
    knn_seg_kernel<<<dim3(N_ / QPB, B_, 3 * (NSEG - 1)), QPB, 0, stream>>>(
        xyz1, xyz2, xyz2w, segD, segI, /*spw=*/NSEG - 1, /*seg_off=*/1, /*warm=*/1);
    knn_merge_kernel<<<dim3(N_ / 256, B_, 3), 256, 0, stream>>>(
        segD, segI, idxA, idxB, idxS);
    mlp2_kernel<<<dim3(N_ / 8, B_, 2), 256, 0, stream>>>(
        xyz1, xyz2, xyz2w, idxA, idxB, G1, P2,
        mlp_W0, mlp_b0, mlp_W1, mlp_b1, feat, featw);
    attn_partial_kernel<<<dim3(NCHUNK, 4 * B_), 256, 0, stream>>>(feat, featw, partial);
    attn_reduce_kernel<<<dim3(CM_, B_), 256, 0, stream>>>(partial, rowsum, colsum);
    cost_kernel<<<dim3(N_ / 4, B_), 256, 0, stream>>>(feat, featw, rowsum, colsum, costT, costwT);
    final_kernel<<<dim3(N_ / 4, B_), 256, 0, stream>>>(xyz1, idxS, costT, costwT,
                                                       wn_W0, wn_b0, wn_g0, wn_be0,
                                                       wn_W1, wn_b1, wn_g1, wn_be1,
                                                       wn_W2, wn_b2, wn_g2, wn_be2, out);
}

// Round 7
// 301.692 us; speedup vs baseline: 1.0656x; 1.0656x over previous
//
#include <hip/hip_runtime.h>
#include <math.h>

#define B_  2
#define N_  4096
#define K_  16
#define D_  64
#define CM_ 64
#define H_  8

// ---------------------------------------------------------------- kNN ------
#define NSEG  16
#define SEGSZ (N_ / NSEG)   // 256
#define QPB   256
#define LIM   16
#define BATCH 8

__device__ __forceinline__ void ce64(unsigned long long& a, unsigned long long& b) {
    bool sw = b < a;
    unsigned long long lo = sw ? b : a;
    unsigned long long hi = sw ? a : b;
    a = lo; b = hi;
}

// Batcher odd-even mergesort n=16: straight-line, literal indices (in-register!)
#define SORT16(e) do { \
    ce64(e[0],e[1]); ce64(e[2],e[3]); ce64(e[4],e[5]); ce64(e[6],e[7]); \
    ce64(e[8],e[9]); ce64(e[10],e[11]); ce64(e[12],e[13]); ce64(e[14],e[15]); \
    ce64(e[0],e[2]); ce64(e[1],e[3]); ce64(e[4],e[6]); ce64(e[5],e[7]); \
    ce64(e[8],e[10]); ce64(e[9],e[11]); ce64(e[12],e[14]); ce64(e[13],e[15]); \
    ce64(e[1],e[2]); ce64(e[5],e[6]); ce64(e[9],e[10]); ce64(e[13],e[14]); \
    ce64(e[0],e[4]); ce64(e[1],e[5]); ce64(e[2],e[6]); ce64(e[3],e[7]); \
    ce64(e[8],e[12]); ce64(e[9],e[13]); ce64(e[10],e[14]); ce64(e[11],e[15]); \
    ce64(e[2],e[4]); ce64(e[3],e[5]); ce64(e[10],e[12]); ce64(e[11],e[13]); \
    ce64(e[1],e[2]); ce64(e[3],e[4]); ce64(e[5],e[6]); \
    ce64(e[9],e[10]); ce64(e[11],e[12]); ce64(e[13],e[14]); \
    ce64(e[0],e[8]); ce64(e[1],e[9]); ce64(e[2],e[10]); ce64(e[3],e[11]); \
    ce64(e[4],e[12]); ce64(e[5],e[13]); ce64(e[6],e[14]); ce64(e[7],e[15]); \
    ce64(e[4],e[8]); ce64(e[5],e[9]); ce64(e[6],e[10]); ce64(e[7],e[11]); \
    ce64(e[2],e[4]); ce64(e[3],e[5]); ce64(e[6],e[8]); ce64(e[7],e[9]); \
    ce64(e[10],e[12]); ce64(e[11],e[13]); \
    ce64(e[1],e[2]); ce64(e[3],e[4]); ce64(e[5],e[6]); ce64(e[7],e[8]); \
    ce64(e[9],e[10]); ce64(e[11],e[12]); ce64(e[13],e[14]); \
} while (0)

// bitonic cleanup n=16 (input bitonic, output sorted asc)
#define BMERGE16(d) do { \
    ce64(d[0],d[8]); ce64(d[1],d[9]); ce64(d[2],d[10]); ce64(d[3],d[11]); \
    ce64(d[4],d[12]); ce64(d[5],d[13]); ce64(d[6],d[14]); ce64(d[7],d[15]); \
    ce64(d[0],d[4]); ce64(d[1],d[5]); ce64(d[2],d[6]); ce64(d[3],d[7]); \
    ce64(d[8],d[12]); ce64(d[9],d[13]); ce64(d[10],d[14]); ce64(d[11],d[15]); \
    ce64(d[0],d[2]); ce64(d[1],d[3]); ce64(d[4],d[6]); ce64(d[5],d[7]); \
    ce64(d[8],d[10]); ce64(d[9],d[11]); ce64(d[12],d[14]); ce64(d[13],d[15]); \
    ce64(d[0],d[1]); ce64(d[2],d[3]); ce64(d[4],d[5]); ce64(d[6],d[7]); \
    ce64(d[8],d[9]); ce64(d[10],d[11]); ce64(d[12],d[13]); ce64(d[14],d[15]); \
} while (0)

// spw = segments-per-which handled by this launch; seg = seg_off + z%spw.
// warm: initialize tau from segment-0's 16th-best distance (conservative
// bound: seg0_d16 >= global_d16; the 2^-10 filter slack admits exact ties).
__global__ __launch_bounds__(256) void knn_seg_kernel(
    const float* __restrict__ xyz1, const float* __restrict__ xyz2,
    const float* __restrict__ xyz2w,
    float* __restrict__ segD, int* __restrict__ segI,
    int spw, int seg_off, int warm)
{
    const int b = blockIdx.y;
    const int which = blockIdx.z / spw;
    const int seg   = seg_off + blockIdx.z % spw;
    const float* q = xyz1 + (size_t)b * 3 * N_;
    const float* r = (which == 0 ? xyz2 : (which == 1 ? xyz2w : xyz1)) + (size_t)b * 3 * N_;

    const int tid = threadIdx.x;
    const int qi = blockIdx.x * QPB + tid;
    const float qx = q[qi], qy = q[N_ + qi], qz = q[2 * N_ + qi];
    const float qq = qx * qx + qy * qy + qz * qz;

    __shared__ float4 tile[SEGSZ];       // 4 KB
    __shared__ float  bufD[LIM * QPB];   // 16 KB, column tid -> bank tid%32
    __shared__ int    bufI[LIM * QPB];   // 16 KB

    unsigned long long bd[K_];           // sorted asc (d_bits<<32 | idx)
#pragma unroll
    for (int i = 0; i < K_; ++i) bd[i] = ~0ull;
    float tau = 3.4e38f;
    if (warm)   // warm start: seg0's 16th-best distance for this query
        tau = segD[((((size_t)b * 3 + which) * NSEG + 0) * N_ + qi) * K_ + (K_ - 1)];
    float c = 0.5f * (qq - tau);
    c -= fabsf(c) * 0.0009765625f + 1e-20f;   // slack: filter never rejects d<=tau
    int cnt = 0;

    const int base0 = seg * SEGSZ;
    for (int j = tid; j < SEGSZ; j += QPB) {
        float x = r[base0 + j], y = r[N_ + base0 + j], z = r[2 * N_ + base0 + j];
        tile[j] = make_float4(x, y, z, x * x + y * y + z * z);
    }
    __syncthreads();

    auto compact = [&](int m_end) {
        unsigned long long e[16];
#pragma unroll
        for (int m = 0; m < 16; ++m) {
            float dv = bufD[m * QPB + tid];
            int   iv = bufI[m * QPB + tid];
            unsigned long long key =
                ((unsigned long long)__float_as_uint(dv) << 32) | (unsigned)iv;
            e[m] = (m < m_end) ? key : ~0ull;
        }
        SORT16(e);                                   // sort 16 (in registers)
#pragma unroll
        for (int i = 0; i < 16; ++i) {               // min-halve vs running top-16
            unsigned long long cand = e[15 - i];
            if (cand < bd[i]) bd[i] = cand;
        }
        BMERGE16(bd);                                // bitonic cleanup
        tau = fminf(tau, __uint_as_float((unsigned)(bd[K_ - 1] >> 32)));
        c = 0.5f * (qq - tau);
        c -= fabsf(c) * 0.0009765625f + 1e-20f;
    };

    // 8-wide batched scan: 8 independent ds_read_b128 in flight per trip,
    // one ballot per 8 refs. Max cnt after a batch = 7 + 8 = 15 < 16.
    for (int j0 = 0; j0 < SEGSZ; j0 += BATCH) {
        float s8[BATCH], d8[BATCH];
#pragma unroll
        for (int u = 0; u < BATCH; ++u) {
            float4 t = tile[j0 + u];
            float dot = qx * t.x + qy * t.y + qz * t.z;
            s8[u] = dot - 0.5f * t.w;
            d8[u] = fmaxf((qq + t.w) - 2.0f * dot, 0.0f);   // canonical d
        }
#pragma unroll
        for (int u = 0; u < BATCH; ++u) {
            if (s8[u] > c) {                  // cheap conservative filter
                bufD[cnt * QPB + tid] = d8[u];
                bufI[cnt * QPB + tid] = base0 + j0 + u;
                ++cnt;
            }
        }
        if (__any(cnt >= 8)) {                // wave-synchronized batch merge
            compact(cnt);
            cnt = 0;
        }
    }
    if (__any(cnt != 0)) compact(cnt);        // skip if nothing buffered

    const size_t ob = ((((size_t)b * 3 + which) * NSEG + seg) * N_ + qi) * K_;
#pragma unroll
    for (int i = 0; i < K_; ++i) {
        segD[ob + i] = __uint_as_float((unsigned)(bd[i] >> 32));
        segI[ob + i] = (int)(unsigned)bd[i];
    }
}

__global__ __launch_bounds__(256) void knn_merge_kernel(
    const float* __restrict__ segD, const int* __restrict__ segI,
    int* __restrict__ idxA, int* __restrict__ idxB, int* __restrict__ idxS)
{
    const int b = blockIdx.y, which = blockIdx.z;
    const int qi = blockIdx.x * 256 + threadIdx.x;
    unsigned long long m[K_];
#pragma unroll
    for (int i = 0; i < K_; ++i) m[i] = ~0ull;
    for (int s = 0; s < NSEG; ++s) {
        const size_t ob = ((((size_t)b * 3 + which) * NSEG + s) * N_ + qi) * K_;
        for (int e = 0; e < K_; ++e) {
            unsigned long long key =
                ((unsigned long long)__float_as_uint(segD[ob + e]) << 32)
                | (unsigned)segI[ob + e];
            if (key >= m[K_ - 1]) break;        // seg list sorted: rest fail too
            m[K_ - 1] = key;
#pragma unroll
            for (int i = K_ - 1; i > 0; --i) {
                if (m[i] < m[i - 1]) {
                    unsigned long long t = m[i]; m[i] = m[i - 1]; m[i - 1] = t;
                }
            }
        }
    }
    int* outp = (which == 0 ? idxA : (which == 1 ? idxB : idxS));
    int* op = outp + ((size_t)b * N_ + qi) * K_;
#pragma unroll
    for (int i = 0; i < K_; ++i) op[i] = (int)(unsigned)m[i];
}

// ----------------------------------------------------- MLP pre-GEMMs -------
// G1[b][n][o] = sum_c points1[b,c,n] * W0[o][c]        (z=0)
// P2[b][n][o] = sum_c points2[b,c,n] * W0[o][64+c]     (z=1)
__global__ __launch_bounds__(256) void pre_gemm_kernel(
    const float* __restrict__ points1, const float* __restrict__ points2,
    const float* __restrict__ W0,
    float* __restrict__ G1, float* __restrict__ P2)
{
    const int b = blockIdx.y, which = blockIdx.z;
    const float* src = which ? points2 : points1;
    float* dst = which ? P2 : G1;
    const int woff = which ? 64 : 0;
    const int n0 = blockIdx.x * 64;
    const int tid = threadIdx.x;

    __shared__ float sW[64 * 65];   // [c][o]
    __shared__ float sA[64 * 68];   // [c][n] pad 68

    for (int i = tid; i < 4096; i += 256) {
        int c = i & 63, o = i >> 6;
        sW[c * 65 + o] = W0[o * 131 + woff + c];
    }
    for (int i = tid; i < 4096; i += 256) {
        int n = i & 63, c = i >> 6;
        sA[c * 68 + n] = src[((size_t)b * 64 + c) * N_ + n0 + n];
    }
    __syncthreads();

    const int o = tid & 63, qg = tid >> 6;
    float acc[16];
#pragma unroll
    for (int j = 0; j < 16; ++j) acc[j] = 0.f;
    for (int c = 0; c < 64; ++c) {
        float w = sW[c * 65 + o];
        const float4* ap = (const float4*)&sA[c * 68 + qg * 16];
#pragma unroll
        for (int m = 0; m < 4; ++m) {
            float4 a4 = ap[m];
            acc[4 * m + 0] += w * a4.x;
            acc[4 * m + 1] += w * a4.y;
            acc[4 * m + 2] += w * a4.z;
            acc[4 * m + 3] += w * a4.w;
        }
    }
#pragma unroll
    for (int j = 0; j < 16; ++j)
        dst[((size_t)b * N_ + n0 + qg * 16 + j) * 64 + o] = acc[j];
}

// ----------------------------------------------------- MLP main ------------
__global__ __launch_bounds__(256) void mlp2_kernel(
    const float* __restrict__ xyz1, const float* __restrict__ xyz2,
    const float* __restrict__ xyz2w,
    const int* __restrict__ idxA, const int* __restrict__ idxB,
    const float* __restrict__ G1, const float* __restrict__ P2,
    const float* __restrict__ W0, const float* __restrict__ b0,
    const float* __restrict__ W1, const float* __restrict__ b1,
    float* __restrict__ feat, float* __restrict__ featw)
{
    const int b = blockIdx.y, which = blockIdx.z;
    const int* idx = which ? idxB : idxA;
    const float* refxyz = (which ? xyz2w : xyz2) + (size_t)b * 3 * N_;
    float* outp = which ? featw : feat;
    const int n0 = blockIdx.x * 8;
    const int tid = threadIdx.x;
    const int w = tid >> 6, lane = tid & 63;

    __shared__ float sh0[64 * 132];   // [c][row]
    __shared__ float sW1[64 * 68];    // [c][o]
    __shared__ float sWc[3 * 64];
    __shared__ float sB0[64];
    __shared__ float sQ[3][8];
    __shared__ int   sIdx[128];

    for (int i = tid; i < 4096; i += 256) {
        int c = i & 63, o = i >> 6;
        sW1[c * 68 + o] = W1[o * 64 + c];
    }
    if (tid < 192) { int m = tid >> 6, o = tid & 63; sWc[m * 64 + o] = W0[o * 131 + 128 + m]; }
    if (tid < 64) sB0[tid] = b0[tid];
    if (tid < 24) { int m = tid >> 3, j = tid & 7; sQ[m][j] = xyz1[((size_t)b * 3 + m) * N_ + n0 + j]; }
    if (tid < 128) sIdx[tid] = idx[((size_t)b * N_ + n0 + (tid >> 4)) * K_ + (tid & 15)];
    __syncthreads();

    {
        const int o = lane;
        const float wc0 = sWc[o], wc1 = sWc[64 + o], wc2 = sWc[128 + o];
        const float bb0 = sB0[o];
#pragma unroll
        for (int p = 0; p < 2; ++p) {
            const int pl = w * 2 + p;
            const float g1 = G1[((size_t)b * N_ + n0 + pl) * 64 + o];
            const float qx = sQ[0][pl], qy = sQ[1][pl], qz = sQ[2][pl];
            for (int k = 0; k < K_; ++k) {
                const int row = pl * K_ + k;
                const int ii = sIdx[row];
                float p2 = P2[((size_t)b * N_ + ii) * 64 + o];
                float dx = refxyz[ii] - qx;
                float dy = refxyz[N_ + ii] - qy;
                float dz = refxyz[2 * N_ + ii] - qz;
                float h = g1 + p2 + dx * wc0 + dy * wc1 + dz * wc2 + bb0;
                h = h >= 0.f ? h : 0.1f * h;
                sh0[o * 132 + row] = h;
            }
        }
    }
    __syncthreads();

    const int lr = lane >> 3, lo = lane & 7;
    float accv[4][8];
    {
        float4 bva = *(const float4*)&b1[lo * 8];
        float4 bvb = *(const float4*)&b1[lo * 8 + 4];
#pragma unroll
        for (int dr = 0; dr < 4; ++dr) {
            accv[dr][0] = bva.x; accv[dr][1] = bva.y; accv[dr][2] = bva.z; accv[dr][3] = bva.w;
            accv[dr][4] = bvb.x; accv[dr][5] = bvb.y; accv[dr][6] = bvb.z; accv[dr][7] = bvb.w;
        }
    }
    for (int c = 0; c < 64; ++c) {
        float4 a4 = *(const float4*)&sh0[c * 132 + w * 32 + lr * 4];
        float4 wa = *(const float4*)&sW1[c * 68 + lo * 8];
        float4 wb = *(const float4*)&sW1[c * 68 + lo * 8 + 4];
        float av[4] = {a4.x, a4.y, a4.z, a4.w};
        float wv[8] = {wa.x, wa.y, wa.z, wa.w, wb.x, wb.y, wb.z, wb.w};
#pragma unroll
        for (int dr = 0; dr < 4; ++dr)
#pragma unroll
            for (int j = 0; j < 8; ++j)
                accv[dr][j] += av[dr] * wv[j];
    }
#pragma unroll
    for (int dr = 0; dr < 4; ++dr) {
        const int row = w * 32 + lr * 4 + dr;
        const int pl = row >> 4, k = row & 15;
        float o8[8];
#pragma unroll
        for (int j = 0; j < 8; ++j) {
            float v = accv[dr][j];
            o8[j] = v >= 0.f ? v : 0.1f * v;
        }
        float* op = outp + (((size_t)b * N_ + n0 + pl) * K_ + k) * 64 + lo * 8;
        *(float4*)op = make_float4(o8[0], o8[1], o8[2], o8[3]);
        *(float4*)(op + 4) = make_float4(o8[4], o8[5], o8[6], o8[7]);
    }
}

// --------------------------------------------------------------- attn ------
#define NCHUNK 32
#define CG 16

__global__ __launch_bounds__(256) void attn_partial_kernel(
    const float* __restrict__ feat, const float* __restrict__ featw,
    float* __restrict__ partial)
{
    const int chunk = blockIdx.x;
    const int b = blockIdx.y >> 2;
    const int c0 = (blockIdx.y & 3) * CG;
    const int tid = threadIdx.x;
    const int k = tid >> 4, c = tid & 15;

    __shared__ float sf[16 * 16 * 17];
    __shared__ float sfw[16 * 16 * 20];

    float acc[K_];
#pragma unroll
    for (int l = 0; l < K_; ++l) acc[l] = 0.f;

    const int n0 = chunk * (N_ / NCHUNK);
    for (int ns = 0; ns < N_ / NCHUNK; ns += 16) {
        __syncthreads();
        for (int i = tid; i < 4096; i += 256) {
            int nn = i >> 8, p = (i >> 4) & 15, qv = i & 15;
            size_t base = (((size_t)b * N_ + n0 + ns + nn) * K_ + p) * CM_ + c0 + qv;
            sf[nn * 272 + p * 17 + qv]  = feat[base];
            sfw[nn * 320 + qv * 20 + p] = featw[base];
        }
        __syncthreads();
#pragma unroll
        for (int nn = 0; nn < 16; ++nn) {
            float f = sf[nn * 272 + k * 17 + c];
            const float4* fp = (const float4*)&sfw[nn * 320 + c * 20];
#pragma unroll
            for (int m = 0; m < 4; ++m) {
                float4 v = fp[m];
                acc[4 * m + 0] += f * v.x;
                acc[4 * m + 1] += f * v.y;
                acc[4 * m + 2] += f * v.z;
                acc[4 * m + 3] += f * v.w;
            }
        }
    }
    float* pp = partial + ((((size_t)b * NCHUNK + chunk) * CM_ + (c0 + c)) * K_ + k) * K_;
#pragma unroll
    for (int m = 0; m < 4; ++m)
        *(float4*)(pp + 4 * m) = make_float4(acc[4 * m], acc[4 * m + 1], acc[4 * m + 2], acc[4 * m + 3]);
}

__global__ __launch_bounds__(256) void attn_reduce_kernel(
    const float* __restrict__ partial,
    float* __restrict__ rowsum, float* __restrict__ colsum)
{
    const int c = blockIdx.x, b = blockIdx.y;
    const int tid = threadIdx.x;
    const int k = tid >> 4, l = tid & 15;
    __shared__ float smat[K_][K_ + 1];

    float acc = 0.f;
#pragma unroll
    for (int ch = 0; ch < NCHUNK; ++ch)
        acc += partial[((((size_t)b * NCHUNK + ch) * CM_ + c) * K_ + k) * K_ + l];

    float m = acc;
#pragma unroll
    for (int off = 8; off >= 1; off >>= 1) m = fmaxf(m, __shfl_xor(m, off, 16));
    float e = expf(acc - m);
    float s = e;
#pragma unroll
    for (int off = 8; off >= 1; off >>= 1) s += __shfl_xor(s, off, 16);
    float sm = fmaxf((e / s) * 0.57735026918962576f, 1e-10f);

    float rs = sm;
#pragma unroll
    for (int off = 8; off >= 1; off >>= 1) rs += __shfl_xor(rs, off, 16);
    if (l == 0) rowsum[((size_t)b * CM_ + c) * K_ + k] = rs;

    smat[k][l] = sm;
    __syncthreads();
    if (tid < K_) {
        float cs = 0.f;
#pragma unroll
        for (int kk = 0; kk < K_; ++kk) cs += smat[kk][tid];
        colsum[((size_t)b * CM_ + c) * K_ + tid] = cs;
    }
}

// --------------------------------------------------------------- cost ------
__global__ __launch_bounds__(256) void cost_kernel(
    const float* __restrict__ feat, const float* __restrict__ featw,
    const float* __restrict__ rowsum, const float* __restrict__ colsum,
    float* __restrict__ costT, float* __restrict__ costwT)
{
    const int b = blockIdx.y;
    const int tid = threadIdx.x;
    __shared__ float scs[64][K_ + 1], srs[64][K_ + 1];
    for (int i = tid; i < 64 * K_; i += 256) {
        int cc = i >> 4, j = i & 15;
        scs[cc][j] = colsum[((size_t)b * CM_ + cc) * K_ + j];
        srs[cc][j] = rowsum[((size_t)b * CM_ + cc) * K_ + j];
    }
    __syncthreads();
    const int ng = tid >> 6, c = tid & 63;
    const int n = blockIdx.x * 4 + ng;
    const float* fp  = feat  + (((size_t)b * N_ + n) * K_) * 64 + c;
    const float* fwp = featw + (((size_t)b * N_ + n) * K_) * 64 + c;
    float a = 0.f, aw = 0.f;
#pragma unroll
    for (int j = 0; j < K_; ++j) {
        a  += fp[j * 64]  * scs[c][j];
        aw += fwp[j * 64] * srs[c][j];
    }
    costT[((size_t)b * N_ + n) * 64 + c]  = a;
    costwT[((size_t)b * N_ + n) * 64 + c] = aw;
}

// -------------------------------------------------------------- final ------
__global__ __launch_bounds__(256) void final_kernel(
    const float* __restrict__ xyz1,
    const int* __restrict__ idxS,
    const float* __restrict__ costT, const float* __restrict__ costwT,
    const float* __restrict__ wn_W0, const float* __restrict__ wn_b0,
    const float* __restrict__ wn_g0, const float* __restrict__ wn_be0,
    const float* __restrict__ wn_W1, const float* __restrict__ wn_b1,
    const float* __restrict__ wn_g1, const float* __restrict__ wn_be1,
    const float* __restrict__ wn_W2, const float* __restrict__ wn_b2,
    const float* __restrict__ wn_g2, const float* __restrict__ wn_be2,
    float* __restrict__ out)
{
    const int b = blockIdx.y;
    const int tid = threadIdx.x;
    const int ng = tid >> 6, c = tid & 63;
    const int n = blockIdx.x * 4 + ng;
    const float invs = 1.0f / sqrtf(1.0f + 1e-5f);

    __shared__ int   sI[4][K_];
    __shared__ float sH1[4][K_][H_];

    if (c < K_) {
        const int k = c;
        const float* qb = xyz1 + (size_t)b * 3 * N_;
        int ii = idxS[((size_t)b * N_ + n) * K_ + k];
        sI[ng][k] = ii;
        float dx = qb[ii] - qb[n];
        float dy = qb[N_ + ii] - qb[N_ + n];
        float dz = qb[2 * N_ + ii] - qb[2 * N_ + n];
        float h0[H_];
#pragma unroll
        for (int o = 0; o < H_; ++o) {
            float v = wn_W0[o * 3] * dx + wn_W0[o * 3 + 1] * dy + wn_W0[o * 3 + 2] * dz + wn_b0[o];
            v = v * (wn_g0[o] * invs) + wn_be0[o];
            h0[o] = fmaxf(v, 0.f);
        }
#pragma unroll
        for (int o = 0; o < H_; ++o) {
            float v = wn_b1[o];
#pragma unroll
            for (int j = 0; j < H_; ++j) v += wn_W1[o * H_ + j] * h0[j];
            v = v * (wn_g1[o] * invs) + wn_be1[o];
            sH1[ng][k][o] = fmaxf(v, 0.f);
        }
    }
    __syncthreads();

    float w2r[H_];
#pragma unroll
    for (int j = 0; j < H_; ++j) w2r[j] = wn_W2[c * H_ + j];
    const float b2v = wn_b2[c];
    const float s2v = wn_g2[c] * invs;
    const float t2v = wn_be2[c];

    float acc = 0.f;
#pragma unroll
    for (int k = 0; k < K_; ++k) {
        float v = b2v;
#pragma unroll
        for (int j = 0; j < H_; ++j) v += w2r[j] * sH1[ng][k][j];
        float wv = fmaxf(v * s2v + t2v, 0.f);
        int ii = sI[ng][k];
        size_t base = ((size_t)b * N_ + ii) * 64 + c;
        acc += wv * (costT[base] + costwT[base]);
    }
    out[((size_t)b * CM_ + c) * N_ + n] = acc;
}

// ------------------------------------------------------------- launch ------
extern "C" void kernel_launch(void* const* d_in, const int* in_sizes, int n_in,
                              void* d_out, int out_size, void* d_ws, size_t ws_size,
                              hipStream_t stream)
{
    const float* xyz1    = (const float*)d_in[0];
    const float* xyz2    = (const float*)d_in[1];
    const float* xyz2w   = (const float*)d_in[2];
    const float* points1 = (const float*)d_in[3];
    const float* points2 = (const float*)d_in[4];
    const float* mlp_W0  = (const float*)d_in[5];
    const float* mlp_b0  = (const float*)d_in[6];
    const float* mlp_W1  = (const float*)d_in[7];
    const float* mlp_b1  = (const float*)d_in[8];
    const float* wn_W0   = (const float*)d_in[9];
    const float* wn_b0   = (const float*)d_in[10];
    const float* wn_g0   = (const float*)d_in[11];
    const float* wn_be0  = (const float*)d_in[12];
    const float* wn_W1   = (const float*)d_in[13];
    const float* wn_b1   = (const float*)d_in[14];
    const float* wn_g1   = (const float*)d_in[15];
    const float* wn_be1  = (const float*)d_in[16];
    const float* wn_W2   = (const float*)d_in[17];
    const float* wn_b2   = (const float*)d_in[18];
    const float* wn_g2   = (const float*)d_in[19];
    const float* wn_be2  = (const float*)d_in[20];
    float* out = (float*)d_out;

    char* ws = (char*)d_ws;
    size_t off = 0;
    auto alloc = [&](size_t bytes) -> void* {
        void* p = ws + off;
        off += (bytes + 255) & ~(size_t)255;
        return p;
    };
    int*   idxA   = (int*)  alloc((size_t)B_ * N_ * K_ * sizeof(int));
    int*   idxB   = (int*)  alloc((size_t)B_ * N_ * K_ * sizeof(int));
    int*   idxS   = (int*)  alloc((size_t)B_ * N_ * K_ * sizeof(int));
    float* feat   = (float*)alloc((size_t)B_ * N_ * K_ * CM_ * sizeof(float));
    float* featw  = (float*)alloc((size_t)B_ * N_ * K_ * CM_ * sizeof(float));
    float* rowsum = (float*)alloc((size_t)B_ * CM_ * K_ * sizeof(float));
    float* colsum = (float*)alloc((size_t)B_ * CM_ * K_ * sizeof(float));
    float* costT  = (float*)alloc((size_t)B_ * N_ * CM_ * sizeof(float));
    float* costwT = (float*)alloc((size_t)B_ * N_ * CM_ * sizeof(float));
    (void)ws_size; (void)in_sizes; (void)n_in; (void)out_size;

    // Aliases, lifetimes chained by stream order (see earlier rounds).
    // segD/segI now [B][3][16][N][K] = 25.2 MB each, still < feat/featw 33.5 MB.
    float* segD    = feat;
    int*   segI    = (int*)featw;
    float* G1      = costT;
    float* P2      = costwT;
    float* partial = costT;

    pre_gemm_kernel<<<dim3(N_ / 64, B_, 2), 256, 0, stream>>>(points1, points2, mlp_W0, G1, P2);
    // phase 1: segment 0 (256 refs), cold start (computes per-query tau)
    knn_seg_kernel<<<dim3(N_ / QPB, B_, 3), QPB, 0, stream>>>(
        xyz1, xyz2, xyz2w, segD, segI, /*spw=*/1, /*seg_off=*/0, /*warm=*/0);
    // phase 2: segments 1..15, warm-started from seg0's tau
    knn_seg_kernel<<<dim3(N_ / QPB, B_, 3 * (NSEG - 1)), QPB, 0, stream>>>(
        xyz1, xyz2, xyz2w, segD, segI, /*spw=*/NSEG - 1, /*seg_off=*/1, /*warm=*/1);
    knn_merge_kernel<<<dim3(N_ / 256, B_, 3), 256, 0, stream>>>(
        segD, segI, idxA, idxB, idxS);
    mlp2_kernel<<<dim3(N_ / 8, B_, 2), 256, 0, stream>>>(
        xyz1, xyz2, xyz2w, idxA, idxB, G1, P2,
        mlp_W0, mlp_b0, mlp_W1, mlp_b1, feat, featw);
    attn_partial_kernel<<<dim3(NCHUNK, 4 * B_), 256, 0, stream>>>(feat, featw, partial);
    attn_reduce_kernel<<<dim3(CM_, B_), 256, 0, stream>>>(partial, rowsum, colsum);
    cost_kernel<<<dim3(N_ / 4, B_), 256, 0, stream>>>(feat, featw, rowsum, colsum, costT, costwT);
    final_kernel<<<dim3(N_ / 4, B_), 256, 0, stream>>>(xyz1, idxS, costT, costwT,
                                                       wn_W0, wn_b0, wn_g0, wn_be0,
                                                       wn_W1, wn_b1, wn_g1, wn_be1,
                                                       wn_W2, wn_b2, wn_g2, wn_be2, out);
}

// Round 8
// 253.568 us; speedup vs baseline: 1.2679x; 1.1898x over previous
//
#include <hip/hip_runtime.h>
#include <math.h>

#define B_  2
#define N_  4096
#define K_  16
#define D_  64
#define CM_ 64
#define H_  8

// ---------------------------------------------------------------- kNN ------
#define NSEG  8
#define SEGSZ (N_ / NSEG)   // 512
#define QPB   256
#define LIM   16
#define BATCH 8
#define TAUS  512           // tau-sample size

__device__ __forceinline__ void ce64(unsigned long long& a, unsigned long long& b) {
    bool sw = b < a;
    unsigned long long lo = sw ? b : a;
    unsigned long long hi = sw ? a : b;
    a = lo; b = hi;
}
__device__ __forceinline__ void cef(float& a, float& b) {
    float lo = fminf(a, b), hi = fmaxf(a, b);
    a = lo; b = hi;
}

// Batcher odd-even mergesort n=16: straight-line, literal indices (in-register!)
#define SORT16_(e, CE) do { \
    CE(e[0],e[1]); CE(e[2],e[3]); CE(e[4],e[5]); CE(e[6],e[7]); \
    CE(e[8],e[9]); CE(e[10],e[11]); CE(e[12],e[13]); CE(e[14],e[15]); \
    CE(e[0],e[2]); CE(e[1],e[3]); CE(e[4],e[6]); CE(e[5],e[7]); \
    CE(e[8],e[10]); CE(e[9],e[11]); CE(e[12],e[14]); CE(e[13],e[15]); \
    CE(e[1],e[2]); CE(e[5],e[6]); CE(e[9],e[10]); CE(e[13],e[14]); \
    CE(e[0],e[4]); CE(e[1],e[5]); CE(e[2],e[6]); CE(e[3],e[7]); \
    CE(e[8],e[12]); CE(e[9],e[13]); CE(e[10],e[14]); CE(e[11],e[15]); \
    CE(e[2],e[4]); CE(e[3],e[5]); CE(e[10],e[12]); CE(e[11],e[13]); \
    CE(e[1],e[2]); CE(e[3],e[4]); CE(e[5],e[6]); \
    CE(e[9],e[10]); CE(e[11],e[12]); CE(e[13],e[14]); \
    CE(e[0],e[8]); CE(e[1],e[9]); CE(e[2],e[10]); CE(e[3],e[11]); \
    CE(e[4],e[12]); CE(e[5],e[13]); CE(e[6],e[14]); CE(e[7],e[15]); \
    CE(e[4],e[8]); CE(e[5],e[9]); CE(e[6],e[10]); CE(e[7],e[11]); \
    CE(e[2],e[4]); CE(e[3],e[5]); CE(e[6],e[8]); CE(e[7],e[9]); \
    CE(e[10],e[12]); CE(e[11],e[13]); \
    CE(e[1],e[2]); CE(e[3],e[4]); CE(e[5],e[6]); CE(e[7],e[8]); \
    CE(e[9],e[10]); CE(e[11],e[12]); CE(e[13],e[14]); \
} while (0)

// bitonic cleanup n=16 (input bitonic, output sorted asc)
#define BMERGE16_(d, CE) do { \
    CE(d[0],d[8]); CE(d[1],d[9]); CE(d[2],d[10]); CE(d[3],d[11]); \
    CE(d[4],d[12]); CE(d[5],d[13]); CE(d[6],d[14]); CE(d[7],d[15]); \
    CE(d[0],d[4]); CE(d[1],d[5]); CE(d[2],d[6]); CE(d[3],d[7]); \
    CE(d[8],d[12]); CE(d[9],d[13]); CE(d[10],d[14]); CE(d[11],d[15]); \
    CE(d[0],d[2]); CE(d[1],d[3]); CE(d[4],d[6]); CE(d[5],d[7]); \
    CE(d[8],d[10]); CE(d[9],d[11]); CE(d[12],d[14]); CE(d[13],d[15]); \
    CE(d[0],d[1]); CE(d[2],d[3]); CE(d[4],d[5]); CE(d[6],d[7]); \
    CE(d[8],d[9]); CE(d[10],d[11]); CE(d[12],d[13]); CE(d[14],d[15]); \
} while (0)

// ---- tau kernel: exact 16th-best DISTANCE over refs [0, TAUS) (f32 keys,
// no indices -> 2-instr compare-exchange; ~3x cheaper compacts).
__global__ __launch_bounds__(256) void knn_tau_kernel(
    const float* __restrict__ xyz1, const float* __restrict__ xyz2,
    const float* __restrict__ xyz2w,
    float* __restrict__ tauBuf)
{
    const int b = blockIdx.y, which = blockIdx.z;
    const float* q = xyz1 + (size_t)b * 3 * N_;
    const float* r = (which == 0 ? xyz2 : (which == 1 ? xyz2w : xyz1)) + (size_t)b * 3 * N_;

    const int tid = threadIdx.x;
    const int qi = blockIdx.x * QPB + tid;
    const float qx = q[qi], qy = q[N_ + qi], qz = q[2 * N_ + qi];
    const float qq = qx * qx + qy * qy + qz * qz;

    __shared__ float4 tile[TAUS];        // 8 KB
    __shared__ float  bufD[LIM * QPB];   // 16 KB

    float bd[K_];
#pragma unroll
    for (int i = 0; i < K_; ++i) bd[i] = 3.4e38f;
    float tau = 3.4e38f;
    float c = 0.5f * (qq - tau);
    c -= fabsf(c) * 0.0009765625f + 1e-20f;
    int cnt = 0;

    for (int j = tid; j < TAUS; j += QPB) {
        float x = r[j], y = r[N_ + j], z = r[2 * N_ + j];
        tile[j] = make_float4(x, y, z, x * x + y * y + z * z);
    }
    __syncthreads();

    auto compactF = [&](int m_end) {
        float e[16];
#pragma unroll
        for (int m = 0; m < 16; ++m) {
            float dv = bufD[m * QPB + tid];
            e[m] = (m < m_end) ? dv : 3.4e38f;
        }
        SORT16_(e, cef);
#pragma unroll
        for (int i = 0; i < 16; ++i) bd[i] = fminf(bd[i], e[15 - i]);
        BMERGE16_(bd, cef);
        tau = fminf(tau, bd[K_ - 1]);
        c = 0.5f * (qq - tau);
        c -= fabsf(c) * 0.0009765625f + 1e-20f;
    };

    for (int j0 = 0; j0 < TAUS; j0 += BATCH) {
        float s8[BATCH], d8[BATCH];
#pragma unroll
        for (int u = 0; u < BATCH; ++u) {
            float4 t = tile[j0 + u];
            float dot = qx * t.x + qy * t.y + qz * t.z;
            s8[u] = dot - 0.5f * t.w;
            d8[u] = fmaxf((qq + t.w) - 2.0f * dot, 0.0f);
        }
#pragma unroll
        for (int u = 0; u < BATCH; ++u) {
            if (s8[u] > c) { bufD[cnt * QPB + tid] = d8[u]; ++cnt; }
        }
        if (__any(cnt > 8)) { compactF(cnt); cnt = 0; }   // cap 16 = 8 + 8
    }
    if (__any(cnt != 0)) compactF(cnt);

    tauBuf[((size_t)b * 3 + which) * N_ + qi] = bd[K_ - 1];
}

// ---- main segmented scan: ALL segments warm from tauBuf. tau >= global d16
// (16th of a subset), so the slacked filter never rejects a true top-16.
__global__ __launch_bounds__(256) void knn_seg_kernel(
    const float* __restrict__ xyz1, const float* __restrict__ xyz2,
    const float* __restrict__ xyz2w,
    const float* __restrict__ tauBuf,
    float* __restrict__ segD, int* __restrict__ segI)
{
    const int b = blockIdx.y;
    const int which = blockIdx.z >> 3;      // 0,1,2
    const int seg   = blockIdx.z & 7;
    const float* q = xyz1 + (size_t)b * 3 * N_;
    const float* r = (which == 0 ? xyz2 : (which == 1 ? xyz2w : xyz1)) + (size_t)b * 3 * N_;

    const int tid = threadIdx.x;
    const int qi = blockIdx.x * QPB + tid;
    const float qx = q[qi], qy = q[N_ + qi], qz = q[2 * N_ + qi];
    const float qq = qx * qx + qy * qy + qz * qz;

    __shared__ float4 tile[SEGSZ];       // 8 KB
    __shared__ float  bufD[LIM * QPB];   // 16 KB
    __shared__ int    bufI[LIM * QPB];   // 16 KB

    unsigned long long bd[K_];           // sorted asc (d_bits<<32 | idx)
#pragma unroll
    for (int i = 0; i < K_; ++i) bd[i] = ~0ull;
    float tau = tauBuf[((size_t)b * 3 + which) * N_ + qi];
    float c = 0.5f * (qq - tau);
    c -= fabsf(c) * 0.0009765625f + 1e-20f;   // slack: never rejects d<=tau
    int cnt = 0;

    const int base0 = seg * SEGSZ;
    for (int j = tid; j < SEGSZ; j += QPB) {
        float x = r[base0 + j], y = r[N_ + base0 + j], z = r[2 * N_ + base0 + j];
        tile[j] = make_float4(x, y, z, x * x + y * y + z * z);
    }
    __syncthreads();

    auto compact = [&](int m_end) {
        unsigned long long e[16];
#pragma unroll
        for (int m = 0; m < 16; ++m) {
            float dv = bufD[m * QPB + tid];
            int   iv = bufI[m * QPB + tid];
            unsigned long long key =
                ((unsigned long long)__float_as_uint(dv) << 32) | (unsigned)iv;
            e[m] = (m < m_end) ? key : ~0ull;
        }
        SORT16_(e, ce64);
#pragma unroll
        for (int i = 0; i < 16; ++i) {
            unsigned long long cand = e[15 - i];
            if (cand < bd[i]) bd[i] = cand;
        }
        BMERGE16_(bd, ce64);
        tau = fminf(tau, __uint_as_float((unsigned)(bd[K_ - 1] >> 32)));
        c = 0.5f * (qq - tau);
        c -= fabsf(c) * 0.0009765625f + 1e-20f;
    };

    for (int j0 = 0; j0 < SEGSZ; j0 += BATCH) {
        float s8[BATCH], d8[BATCH];
#pragma unroll
        for (int u = 0; u < BATCH; ++u) {
            float4 t = tile[j0 + u];
            float dot = qx * t.x + qy * t.y + qz * t.z;
            s8[u] = dot - 0.5f * t.w;
            d8[u] = fmaxf((qq + t.w) - 2.0f * dot, 0.0f);
        }
#pragma unroll
        for (int u = 0; u < BATCH; ++u) {
            if (s8[u] > c) {
                bufD[cnt * QPB + tid] = d8[u];
                bufI[cnt * QPB + tid] = base0 + j0 + u;
                ++cnt;
            }
        }
        if (__any(cnt > 8)) { compact(cnt); cnt = 0; }    // cap 16 = 8 + 8
    }
    if (__any(cnt != 0)) compact(cnt);

    const size_t ob = ((((size_t)b * 3 + which) * NSEG + seg) * N_ + qi) * K_;
#pragma unroll
    for (int i = 0; i < K_; ++i) {
        segD[ob + i] = __uint_as_float((unsigned)(bd[i] >> 32));
        segI[ob + i] = (int)(unsigned)bd[i];
    }
}

__global__ __launch_bounds__(256) void knn_merge_kernel(
    const float* __restrict__ segD, const int* __restrict__ segI,
    int* __restrict__ idxA, int* __restrict__ idxB, int* __restrict__ idxS)
{
    const int b = blockIdx.y, which = blockIdx.z;
    const int qi = blockIdx.x * 256 + threadIdx.x;
    unsigned long long m[K_];
#pragma unroll
    for (int i = 0; i < K_; ++i) m[i] = ~0ull;
    for (int s = 0; s < NSEG; ++s) {
        const size_t ob = ((((size_t)b * 3 + which) * NSEG + s) * N_ + qi) * K_;
        for (int e = 0; e < K_; ++e) {
            unsigned long long key =
                ((unsigned long long)__float_as_uint(segD[ob + e]) << 32)
                | (unsigned)segI[ob + e];
            if (key >= m[K_ - 1]) break;        // seg list sorted: rest fail too
            m[K_ - 1] = key;
#pragma unroll
            for (int i = K_ - 1; i > 0; --i) {
                if (m[i] < m[i - 1]) {
                    unsigned long long t = m[i]; m[i] = m[i - 1]; m[i - 1] = t;
                }
            }
        }
    }
    int* outp = (which == 0 ? idxA : (which == 1 ? idxB : idxS));
    int* op = outp + ((size_t)b * N_ + qi) * K_;
#pragma unroll
    for (int i = 0; i < K_; ++i) op[i] = (int)(unsigned)m[i];
}

// ----------------------------------------------------- MLP pre-GEMMs -------
// G1[b][n][o] = sum_c points1[b,c,n] * W0[o][c]        (z=0)
// P2[b][n][o] = sum_c points2[b,c,n] * W0[o][64+c]     (z=1)
__global__ __launch_bounds__(256) void pre_gemm_kernel(
    const float* __restrict__ points1, const float* __restrict__ points2,
    const float* __restrict__ W0,
    float* __restrict__ G1, float* __restrict__ P2)
{
    const int b = blockIdx.y, which = blockIdx.z;
    const float* src = which ? points2 : points1;
    float* dst = which ? P2 : G1;
    const int woff = which ? 64 : 0;
    const int n0 = blockIdx.x * 64;
    const int tid = threadIdx.x;

    __shared__ float sW[64 * 65];   // [c][o]
    __shared__ float sA[64 * 68];   // [c][n] pad 68

    for (int i = tid; i < 4096; i += 256) {
        int c = i & 63, o = i >> 6;
        sW[c * 65 + o] = W0[o * 131 + woff + c];
    }
    for (int i = tid; i < 4096; i += 256) {
        int n = i & 63, c = i >> 6;
        sA[c * 68 + n] = src[((size_t)b * 64 + c) * N_ + n0 + n];
    }
    __syncthreads();

    const int o = tid & 63, qg = tid >> 6;
    float acc[16];
#pragma unroll
    for (int j = 0; j < 16; ++j) acc[j] = 0.f;
    for (int c = 0; c < 64; ++c) {
        float w = sW[c * 65 + o];
        const float4* ap = (const float4*)&sA[c * 68 + qg * 16];
#pragma unroll
        for (int m = 0; m < 4; ++m) {
            float4 a4 = ap[m];
            acc[4 * m + 0] += w * a4.x;
            acc[4 * m + 1] += w * a4.y;
            acc[4 * m + 2] += w * a4.z;
            acc[4 * m + 3] += w * a4.w;
        }
    }
#pragma unroll
    for (int j = 0; j < 16; ++j)
        dst[((size_t)b * N_ + n0 + qg * 16 + j) * 64 + o] = acc[j];
}

// ----------------------------------------------------- MLP main ------------
__global__ __launch_bounds__(256) void mlp2_kernel(
    const float* __restrict__ xyz1, const float* __restrict__ xyz2,
    const float* __restrict__ xyz2w,
    const int* __restrict__ idxA, const int* __restrict__ idxB,
    const float* __restrict__ G1, const float* __restrict__ P2,
    const float* __restrict__ W0, const float* __restrict__ b0,
    const float* __restrict__ W1, const float* __restrict__ b1,
    float* __restrict__ feat, float* __restrict__ featw)
{
    const int b = blockIdx.y, which = blockIdx.z;
    const int* idx = which ? idxB : idxA;
    const float* refxyz = (which ? xyz2w : xyz2) + (size_t)b * 3 * N_;
    float* outp = which ? featw : feat;
    const int n0 = blockIdx.x * 8;
    const int tid = threadIdx.x;
    const int w = tid >> 6, lane = tid & 63;

    __shared__ float sh0[64 * 132];   // [c][row]
    __shared__ float sW1[64 * 68];    // [c][o]
    __shared__ float sWc[3 * 64];
    __shared__ float sB0[64];
    __shared__ float sQ[3][8];
    __shared__ int   sIdx[128];

    for (int i = tid; i < 4096; i += 256) {
        int c = i & 63, o = i >> 6;
        sW1[c * 68 + o] = W1[o * 64 + c];
    }
    if (tid < 192) { int m = tid >> 6, o = tid & 63; sWc[m * 64 + o] = W0[o * 131 + 128 + m]; }
    if (tid < 64) sB0[tid] = b0[tid];
    if (tid < 24) { int m = tid >> 3, j = tid & 7; sQ[m][j] = xyz1[((size_t)b * 3 + m) * N_ + n0 + j]; }
    if (tid < 128) sIdx[tid] = idx[((size_t)b * N_ + n0 + (tid >> 4)) * K_ + (tid & 15)];
    __syncthreads();

    {
        const int o = lane;
        const float wc0 = sWc[o], wc1 = sWc[64 + o], wc2 = sWc[128 + o];
        const float bb0 = sB0[o];
#pragma unroll
        for (int p = 0; p < 2; ++p) {
            const int pl = w * 2 + p;
            const float g1 = G1[((size_t)b * N_ + n0 + pl) * 64 + o];
            const float qx = sQ[0][pl], qy = sQ[1][pl], qz = sQ[2][pl];
            for (int k = 0; k < K_; ++k) {
                const int row = pl * K_ + k;
                const int ii = sIdx[row];
                float p2 = P2[((size_t)b * N_ + ii) * 64 + o];
                float dx = refxyz[ii] - qx;
                float dy = refxyz[N_ + ii] - qy;
                float dz = refxyz[2 * N_ + ii] - qz;
                float h = g1 + p2 + dx * wc0 + dy * wc1 + dz * wc2 + bb0;
                h = h >= 0.f ? h : 0.1f * h;
                sh0[o * 132 + row] = h;
            }
        }
    }
    __syncthreads();

    const int lr = lane >> 3, lo = lane & 7;
    float accv[4][8];
    {
        float4 bva = *(const float4*)&b1[lo * 8];
        float4 bvb = *(const float4*)&b1[lo * 8 + 4];
#pragma unroll
        for (int dr = 0; dr < 4; ++dr) {
            accv[dr][0] = bva.x; accv[dr][1] = bva.y; accv[dr][2] = bva.z; accv[dr][3] = bva.w;
            accv[dr][4] = bvb.x; accv[dr][5] = bvb.y; accv[dr][6] = bvb.z; accv[dr][7] = bvb.w;
        }
    }
    for (int c = 0; c < 64; ++c) {
        float4 a4 = *(const float4*)&sh0[c * 132 + w * 32 + lr * 4];
        float4 wa = *(const float4*)&sW1[c * 68 + lo * 8];
        float4 wb = *(const float4*)&sW1[c * 68 + lo * 8 + 4];
        float av[4] = {a4.x, a4.y, a4.z, a4.w};
        float wv[8] = {wa.x, wa.y, wa.z, wa.w, wb.x, wb.y, wb.z, wb.w};
#pragma unroll
        for (int dr = 0; dr < 4; ++dr)
#pragma unroll
            for (int j = 0; j < 8; ++j)
                accv[dr][j] += av[dr] * wv[j];
    }
#pragma unroll
    for (int dr = 0; dr < 4; ++dr) {
        const int row = w * 32 + lr * 4 + dr;
        const int pl = row >> 4, k = row & 15;
        float o8[8];
#pragma unroll
        for (int j = 0; j < 8; ++j) {
            float v = accv[dr][j];
            o8[j] = v >= 0.f ? v : 0.1f * v;
        }
        float* op = outp + (((size_t)b * N_ + n0 + pl) * K_ + k) * 64 + lo * 8;
        *(float4*)op = make_float4(o8[0], o8[1], o8[2], o8[3]);
        *(float4*)(op + 4) = make_float4(o8[4], o8[5], o8[6], o8[7]);
    }
}

// --------------------------------------------------------------- attn ------
#define NCHUNK 32
#define CG 16

__global__ __launch_bounds__(256) void attn_partial_kernel(
    const float* __restrict__ feat, const float* __restrict__ featw,
    float* __restrict__ partial)
{
    const int chunk = blockIdx.x;
    const int b = blockIdx.y >> 2;
    const int c0 = (blockIdx.y & 3) * CG;
    const int tid = threadIdx.x;
    const int k = tid >> 4, c = tid & 15;

    __shared__ float sf[16 * 16 * 17];
    __shared__ float sfw[16 * 16 * 20];

    float acc[K_];
#pragma unroll
    for (int l = 0; l < K_; ++l) acc[l] = 0.f;

    const int n0 = chunk * (N_ / NCHUNK);
    for (int ns = 0; ns < N_ / NCHUNK; ns += 16) {
        __syncthreads();
        for (int i = tid; i < 4096; i += 256) {
            int nn = i >> 8, p = (i >> 4) & 15, qv = i & 15;
            size_t base = (((size_t)b * N_ + n0 + ns + nn) * K_ + p) * CM_ + c0 + qv;
            sf[nn * 272 + p * 17 + qv]  = feat[base];
            sfw[nn * 320 + qv * 20 + p] = featw[base];
        }
        __syncthreads();
#pragma unroll
        for (int nn = 0; nn < 16; ++nn) {
            float f = sf[nn * 272 + k * 17 + c];
            const float4* fp = (const float4*)&sfw[nn * 320 + c * 20];
#pragma unroll
            for (int m = 0; m < 4; ++m) {
                float4 v = fp[m];
                acc[4 * m + 0] += f * v.x;
                acc[4 * m + 1] += f * v.y;
                acc[4 * m + 2] += f * v.z;
                acc[4 * m + 3] += f * v.w;
            }
        }
    }
    float* pp = partial + ((((size_t)b * NCHUNK + chunk) * CM_ + (c0 + c)) * K_ + k) * K_;
#pragma unroll
    for (int m = 0; m < 4; ++m)
        *(float4*)(pp + 4 * m) = make_float4(acc[4 * m], acc[4 * m + 1], acc[4 * m + 2], acc[4 * m + 3]);
}

__global__ __launch_bounds__(256) void attn_reduce_kernel(
    const float* __restrict__ partial,
    float* __restrict__ rowsum, float* __restrict__ colsum)
{
    const int c = blockIdx.x, b = blockIdx.y;
    const int tid = threadIdx.x;
    const int k = tid >> 4, l = tid & 15;
    __shared__ float smat[K_][K_ + 1];

    float acc = 0.f;
#pragma unroll
    for (int ch = 0; ch < NCHUNK; ++ch)
        acc += partial[((((size_t)b * NCHUNK + ch) * CM_ + c) * K_ + k) * K_ + l];

    float m = acc;
#pragma unroll
    for (int off = 8; off >= 1; off >>= 1) m = fmaxf(m, __shfl_xor(m, off, 16));
    float e = expf(acc - m);
    float s = e;
#pragma unroll
    for (int off = 8; off >= 1; off >>= 1) s += __shfl_xor(s, off, 16);
    float sm = fmaxf((e / s) * 0.57735026918962576f, 1e-10f);

    float rs = sm;
#pragma unroll
    for (int off = 8; off >= 1; off >>= 1) rs += __shfl_xor(rs, off, 16);
    if (l == 0) rowsum[((size_t)b * CM_ + c) * K_ + k] = rs;

    smat[k][l] = sm;
    __syncthreads();
    if (tid < K_) {
        float cs = 0.f;
#pragma unroll
        for (int kk = 0; kk < K_; ++kk) cs += smat[kk][tid];
        colsum[((size_t)b * CM_ + c) * K_ + tid] = cs;
    }
}

// --------------------------------------------------------------- cost ------
__global__ __launch_bounds__(256) void cost_kernel(
    const float* __restrict__ feat, const float* __restrict__ featw,
    const float* __restrict__ rowsum, const float* __restrict__ colsum,
    float* __restrict__ costT, float* __restrict__ costwT)
{
    const int b = blockIdx.y;
    const int tid = threadIdx.x;
    __shared__ float scs[64][K_ + 1], srs[64][K_ + 1];
    for (int i = tid; i < 64 * K_; i += 256) {
        int cc = i >> 4, j = i & 15;
        scs[cc][j] = colsum[((size_t)b * CM_ + cc) * K_ + j];
        srs[cc][j] = rowsum[((size_t)b * CM_ + cc) * K_ + j];
    }
    __syncthreads();
    const int ng = tid >> 6, c = tid & 63;
    const int n = blockIdx.x * 4 + ng;
    const float* fp  = feat  + (((size_t)b * N_ + n) * K_) * 64 + c;
    const float* fwp = featw + (((size_t)b * N_ + n) * K_) * 64 + c;
    float a = 0.f, aw = 0.f;
#pragma unroll
    for (int j = 0; j < K_; ++j) {
        a  += fp[j * 64]  * scs[c][j];
        aw += fwp[j * 64] * srs[c][j];
    }
    costT[((size_t)b * N_ + n) * 64 + c]  = a;
    costwT[((size_t)b * N_ + n) * 64 + c] = aw;
}

// -------------------------------------------------------------- final ------
__global__ __launch_bounds__(256) void final_kernel(
    const float* __restrict__ xyz1,
    const int* __restrict__ idxS,
    const float* __restrict__ costT, const float* __restrict__ costwT,
    const float* __restrict__ wn_W0, const float* __restrict__ wn_b0,
    const float* __restrict__ wn_g0, const float* __restrict__ wn_be0,
    const float* __restrict__ wn_W1, const float* __restrict__ wn_b1,
    const float* __restrict__ wn_g1, const float* __restrict__ wn_be1,
    const float* __restrict__ wn_W2, const float* __restrict__ wn_b2,
    const float* __restrict__ wn_g2, const float* __restrict__ wn_be2,
    float* __restrict__ out)
{
    const int b = blockIdx.y;
    const int tid = threadIdx.x;
    const int ng = tid >> 6, c = tid & 63;
    const int n = blockIdx.x * 4 + ng;
    const float invs = 1.0f / sqrtf(1.0f + 1e-5f);

    __shared__ int   sI[4][K_];
    __shared__ float sH1[4][K_][H_];

    if (c < K_) {
        const int k = c;
        const float* qb = xyz1 + (size_t)b * 3 * N_;
        int ii = idxS[((size_t)b * N_ + n) * K_ + k];
        sI[ng][k] = ii;
        float dx = qb[ii] - qb[n];
        float dy = qb[N_ + ii] - qb[N_ + n];
        float dz = qb[2 * N_ + ii] - qb[2 * N_ + n];
        float h0[H_];
#pragma unroll
        for (int o = 0; o < H_; ++o) {
            float v = wn_W0[o * 3] * dx + wn_W0[o * 3 + 1] * dy + wn_W0[o * 3 + 2] * dz + wn_b0[o];
            v = v * (wn_g0[o] * invs) + wn_be0[o];
            h0[o] = fmaxf(v, 0.f);
        }
#pragma unroll
        for (int o = 0; o < H_; ++o) {
            float v = wn_b1[o];
#pragma unroll
            for (int j = 0; j < H_; ++j) v += wn_W1[o * H_ + j] * h0[j];
            v = v * (wn_g1[o] * invs) + wn_be1[o];
            sH1[ng][k][o] = fmaxf(v, 0.f);
        }
    }
    __syncthreads();

    float w2r[H_];
#pragma unroll
    for (int j = 0; j < H_; ++j) w2r[j] = wn_W2[c * H_ + j];
    const float b2v = wn_b2[c];
    const float s2v = wn_g2[c] * invs;
    const float t2v = wn_be2[c];

    float acc = 0.f;
#pragma unroll
    for (int k = 0; k < K_; ++k) {
        float v = b2v;
#pragma unroll
        for (int j = 0; j < H_; ++j) v += w2r[j] * sH1[ng][k][j];
        float wv = fmaxf(v * s2v + t2v, 0.f);
        int ii = sI[ng][k];
        size_t base = ((size_t)b * N_ + ii) * 64 + c;
        acc += wv * (costT[base] + costwT[base]);
    }
    out[((size_t)b * CM_ + c) * N_ + n] = acc;
}

// ------------------------------------------------------------- launch ------
extern "C" void kernel_launch(void* const* d_in, const int* in_sizes, int n_in,
                              void* d_out, int out_size, void* d_ws, size_t ws_size,
                              hipStream_t stream)
{
    const float* xyz1    = (const float*)d_in[0];
    const float* xyz2    = (const float*)d_in[1];
    const float* xyz2w   = (const float*)d_in[2];
    const float* points1 = (const float*)d_in[3];
    const float* points2 = (const float*)d_in[4];
    const float* mlp_W0  = (const float*)d_in[5];
    const float* mlp_b0  = (const float*)d_in[6];
    const float* mlp_W1  = (const float*)d_in[7];
    const float* mlp_b1  = (const float*)d_in[8];
    const float* wn_W0   = (const float*)d_in[9];
    const float* wn_b0   = (const float*)d_in[10];
    const float* wn_g0   = (const float*)d_in[11];
    const float* wn_be0  = (const float*)d_in[12];
    const float* wn_W1   = (const float*)d_in[13];
    const float* wn_b1   = (const float*)d_in[14];
    const float* wn_g1   = (const float*)d_in[15];
    const float* wn_be1  = (const float*)d_in[16];
    const float* wn_W2   = (const float*)d_in[17];
    const float* wn_b2   = (const float*)d_in[18];
    const float* wn_g2   = (const float*)d_in[19];
    const float* wn_be2  = (const float*)d_in[20];
    float* out = (float*)d_out;

    char* ws = (char*)d_ws;
    size_t off = 0;
    auto alloc = [&](size_t bytes) -> void* {
        void* p = ws + off;
        off += (bytes + 255) & ~(size_t)255;
        return p;
    };
    int*   idxA   = (int*)  alloc((size_t)B_ * N_ * K_ * sizeof(int));
    int*   idxB   = (int*)  alloc((size_t)B_ * N_ * K_ * sizeof(int));
    int*   idxS   = (int*)  alloc((size_t)B_ * N_ * K_ * sizeof(int));
    float* tauBuf = (float*)alloc((size_t)B_ * 3 * N_ * sizeof(float));
    float* feat   = (float*)alloc((size_t)B_ * N_ * K_ * CM_ * sizeof(float));
    float* featw  = (float*)alloc((size_t)B_ * N_ * K_ * CM_ * sizeof(float));
    float* rowsum = (float*)alloc((size_t)B_ * CM_ * K_ * sizeof(float));
    float* colsum = (float*)alloc((size_t)B_ * CM_ * K_ * sizeof(float));
    float* costT  = (float*)alloc((size_t)B_ * N_ * CM_ * sizeof(float));
    float* costwT = (float*)alloc((size_t)B_ * N_ * CM_ * sizeof(float));
    (void)ws_size; (void)in_sizes; (void)n_in; (void)out_size;

    // Aliases, lifetimes chained by stream order (see earlier rounds).
    float* segD    = feat;
    int*   segI    = (int*)featw;
    float* G1      = costT;
    float* P2      = costwT;
    float* partial = costT;   // 4.2 MB spans costT+costwT (both dead then)

    pre_gemm_kernel<<<dim3(N_ / 64, B_, 2), 256, 0, stream>>>(points1, points2, mlp_W0, G1, P2);
    knn_tau_kernel<<<dim3(N_ / QPB, B_, 3), QPB, 0, stream>>>(
        xyz1, xyz2, xyz2w, tauBuf);
    knn_seg_kernel<<<dim3(N_ / QPB, B_, 3 * NSEG), QPB, 0, stream>>>(
        xyz1, xyz2, xyz2w, tauBuf, segD, segI);
    knn_merge_kernel<<<dim3(N_ / 256, B_, 3), 256, 0, stream>>>(
        segD, segI, idxA, idxB, idxS);
    mlp2_kernel<<<dim3(N_ / 8, B_, 2), 256, 0, stream>>>(
        xyz1, xyz2, xyz2w, idxA, idxB, G1, P2,
        mlp_W0, mlp_b0, mlp_W1, mlp_b1, feat, featw);
    attn_partial_kernel<<<dim3(NCHUNK, 4 * B_), 256, 0, stream>>>(feat, featw, partial);
    attn_reduce_kernel<<<dim3(CM_, B_), 256, 0, stream>>>(partial, rowsum, colsum);
    cost_kernel<<<dim3(N_ / 4, B_), 256, 0, stream>>>(feat, featw, rowsum, colsum, costT, costwT);
    final_kernel<<<dim3(N_ / 4, B_), 256, 0, stream>>>(xyz1, idxS, costT, costwT,
                                                       wn_W0, wn_b0, wn_g0, wn_be0,
                                                       wn_W1, wn_b1, wn_g1, wn_be1,
                                                       wn_W2, wn_b2, wn_g2, wn_be2, out);
}

// Round 9
// 238.495 us; speedup vs baseline: 1.3480x; 1.0632x over previous
//
#include <hip/hip_runtime.h>
#include <math.h>

#define B_  2
#define N_  4096
#define K_  16
#define D_  64
#define CM_ 64
#define H_  8

// ---------------------------------------------------------------- kNN ------
#define NSEG  8
#define SEGSZ (N_ / NSEG)   // 512
#define QPB   256
#define LIM   16
#define BATCH 8
#define TAUS  512           // tau-sample size

__device__ __forceinline__ void ce64(unsigned long long& a, unsigned long long& b) {
    bool sw = b < a;
    unsigned long long lo = sw ? b : a;
    unsigned long long hi = sw ? a : b;
    a = lo; b = hi;
}
__device__ __forceinline__ void cef(float& a, float& b) {
    float lo = fminf(a, b), hi = fmaxf(a, b);
    a = lo; b = hi;
}

// Batcher odd-even mergesort n=16: straight-line, literal indices (in-register!)
#define SORT16_(e, CE) do { \
    CE(e[0],e[1]); CE(e[2],e[3]); CE(e[4],e[5]); CE(e[6],e[7]); \
    CE(e[8],e[9]); CE(e[10],e[11]); CE(e[12],e[13]); CE(e[14],e[15]); \
    CE(e[0],e[2]); CE(e[1],e[3]); CE(e[4],e[6]); CE(e[5],e[7]); \
    CE(e[8],e[10]); CE(e[9],e[11]); CE(e[12],e[14]); CE(e[13],e[15]); \
    CE(e[1],e[2]); CE(e[5],e[6]); CE(e[9],e[10]); CE(e[13],e[14]); \
    CE(e[0],e[4]); CE(e[1],e[5]); CE(e[2],e[6]); CE(e[3],e[7]); \
    CE(e[8],e[12]); CE(e[9],e[13]); CE(e[10],e[14]); CE(e[11],e[15]); \
    CE(e[2],e[4]); CE(e[3],e[5]); CE(e[10],e[12]); CE(e[11],e[13]); \
    CE(e[1],e[2]); CE(e[3],e[4]); CE(e[5],e[6]); \
    CE(e[9],e[10]); CE(e[11],e[12]); CE(e[13],e[14]); \
    CE(e[0],e[8]); CE(e[1],e[9]); CE(e[2],e[10]); CE(e[3],e[11]); \
    CE(e[4],e[12]); CE(e[5],e[13]); CE(e[6],e[14]); CE(e[7],e[15]); \
    CE(e[4],e[8]); CE(e[5],e[9]); CE(e[6],e[10]); CE(e[7],e[11]); \
    CE(e[2],e[4]); CE(e[3],e[5]); CE(e[6],e[8]); CE(e[7],e[9]); \
    CE(e[10],e[12]); CE(e[11],e[13]); \
    CE(e[1],e[2]); CE(e[3],e[4]); CE(e[5],e[6]); CE(e[7],e[8]); \
    CE(e[9],e[10]); CE(e[11],e[12]); CE(e[13],e[14]); \
} while (0)

// bitonic cleanup n=16 (input bitonic, output sorted asc)
#define BMERGE16_(d, CE) do { \
    CE(d[0],d[8]); CE(d[1],d[9]); CE(d[2],d[10]); CE(d[3],d[11]); \
    CE(d[4],d[12]); CE(d[5],d[13]); CE(d[6],d[14]); CE(d[7],d[15]); \
    CE(d[0],d[4]); CE(d[1],d[5]); CE(d[2],d[6]); CE(d[3],d[7]); \
    CE(d[8],d[12]); CE(d[9],d[13]); CE(d[10],d[14]); CE(d[11],d[15]); \
    CE(d[0],d[2]); CE(d[1],d[3]); CE(d[4],d[6]); CE(d[5],d[7]); \
    CE(d[8],d[10]); CE(d[9],d[11]); CE(d[12],d[14]); CE(d[13],d[15]); \
    CE(d[0],d[1]); CE(d[2],d[3]); CE(d[4],d[5]); CE(d[6],d[7]); \
    CE(d[8],d[9]); CE(d[10],d[11]); CE(d[12],d[13]); CE(d[14],d[15]); \
} while (0)

// ---- tau kernel: exact 16th-best DISTANCE over refs [0, TAUS) (f32 keys).
__global__ __launch_bounds__(256) void knn_tau_kernel(
    const float* __restrict__ xyz1, const float* __restrict__ xyz2,
    const float* __restrict__ xyz2w,
    float* __restrict__ tauBuf)
{
    const int b = blockIdx.y, which = blockIdx.z;
    const float* q = xyz1 + (size_t)b * 3 * N_;
    const float* r = (which == 0 ? xyz2 : (which == 1 ? xyz2w : xyz1)) + (size_t)b * 3 * N_;

    const int tid = threadIdx.x;
    const int qi = blockIdx.x * QPB + tid;
    const float qx = q[qi], qy = q[N_ + qi], qz = q[2 * N_ + qi];
    const float qq = qx * qx + qy * qy + qz * qz;

    __shared__ float4 tile[TAUS];        // {x,y,z,-rr/2}
    __shared__ float  bufS[LIM * QPB];   // stores s; d recovered at compact

    float bd[K_];
#pragma unroll
    for (int i = 0; i < K_; ++i) bd[i] = 3.4e38f;
    float tau = 3.4e38f;
    float c = 0.5f * (qq - tau);
    c -= fabsf(c) * 0.0009765625f + 1e-20f;
    int cnt = 0;

    for (int j = tid; j < TAUS; j += QPB) {
        float x = r[j], y = r[N_ + j], z = r[2 * N_ + j];
        tile[j] = make_float4(x, y, z, -0.5f * (x * x + y * y + z * z));
    }
    __syncthreads();

    auto compactF = [&](int m_end) {
        float e[16];
#pragma unroll
        for (int m = 0; m < 16; ++m) {
            float sv = bufS[m * QPB + tid];
            float dv = fmaxf(qq - 2.0f * sv, 0.0f);   // tau only: rounding ok
            e[m] = (m < m_end) ? dv : 3.4e38f;
        }
        SORT16_(e, cef);
#pragma unroll
        for (int i = 0; i < 16; ++i) bd[i] = fminf(bd[i], e[15 - i]);
        BMERGE16_(bd, cef);
        tau = fminf(tau, bd[K_ - 1]);
        c = 0.5f * (qq - tau);
        c -= fabsf(c) * 0.0009765625f + 1e-20f;
    };

    for (int j0 = 0; j0 < TAUS; j0 += BATCH) {
        float s8[BATCH];
#pragma unroll
        for (int u = 0; u < BATCH; ++u) {
            float4 t = tile[j0 + u];
            s8[u] = qx * t.x + (qy * t.y + (qz * t.z + t.w));  // dot - rr/2
        }
#pragma unroll
        for (int u = 0; u < BATCH; ++u) {
            bufS[cnt * QPB + tid] = s8[u];        // unconditional (branchless)
            cnt += (s8[u] > c) ? 1 : 0;
        }
        if (__any(cnt > 8)) { compactF(cnt); cnt = 0; }   // cap 16 = 8 + 8
    }
    if (__any(cnt != 0)) compactF(cnt);

    tauBuf[((size_t)b * 3 + which) * N_ + qi] = bd[K_ - 1];
}

// ---- main segmented scan, warm from tauBuf. Transposed output [seg][k][N]
// for coalesced writes + coalesced merge reads.
__global__ __launch_bounds__(256) void knn_seg_kernel(
    const float* __restrict__ xyz1, const float* __restrict__ xyz2,
    const float* __restrict__ xyz2w,
    const float* __restrict__ tauBuf,
    float* __restrict__ segD, int* __restrict__ segI)
{
    const int b = blockIdx.y;
    const int which = blockIdx.z >> 3;      // 0,1,2
    const int seg   = blockIdx.z & 7;
    const float* q = xyz1 + (size_t)b * 3 * N_;
    const float* r = (which == 0 ? xyz2 : (which == 1 ? xyz2w : xyz1)) + (size_t)b * 3 * N_;

    const int tid = threadIdx.x;
    const int qi = blockIdx.x * QPB + tid;
    const float qx = q[qi], qy = q[N_ + qi], qz = q[2 * N_ + qi];
    const float qq = qx * qx + qy * qy + qz * qz;

    __shared__ float4 tile[SEGSZ];       // {x,y,z,-rr/2}  8 KB
    __shared__ int    bufI[LIM * QPB];   // 16 KB (local ref idx only)

    unsigned long long bd[K_];           // sorted asc (d_bits<<32 | idx)
#pragma unroll
    for (int i = 0; i < K_; ++i) bd[i] = ~0ull;
    float tau = tauBuf[((size_t)b * 3 + which) * N_ + qi];
    float c = 0.5f * (qq - tau);
    c -= fabsf(c) * 0.0009765625f + 1e-20f;   // slack: never rejects d<=tau
    int cnt = 0;

    const int base0 = seg * SEGSZ;
    for (int j = tid; j < SEGSZ; j += QPB) {
        float x = r[base0 + j], y = r[N_ + base0 + j], z = r[2 * N_ + base0 + j];
        tile[j] = make_float4(x, y, z, -0.5f * (x * x + y * y + z * z));
    }
    __syncthreads();

    auto compact = [&](int m_end) {
        unsigned long long e[16];
#pragma unroll
        for (int m = 0; m < 16; ++m) {
            int j = bufI[m * QPB + tid] & (SEGSZ - 1);      // in-range always
            float4 t = tile[j];
            float dot = qx * t.x + qy * t.y + qz * t.z;     // original order
            float rr = -2.0f * t.w;                          // exact recover
            float dv = fmaxf((qq + rr) - 2.0f * dot, 0.0f);  // canonical bits
            unsigned long long key =
                ((unsigned long long)__float_as_uint(dv) << 32)
                | (unsigned)(base0 + j);
            e[m] = (m < m_end) ? key : ~0ull;
        }
        SORT16_(e, ce64);
#pragma unroll
        for (int i = 0; i < 16; ++i) {
            unsigned long long cand = e[15 - i];
            if (cand < bd[i]) bd[i] = cand;
        }
        BMERGE16_(bd, ce64);
        tau = fminf(tau, __uint_as_float((unsigned)(bd[K_ - 1] >> 32)));
        c = 0.5f * (qq - tau);
        c -= fabsf(c) * 0.0009765625f + 1e-20f;
    };

    for (int j0 = 0; j0 < SEGSZ; j0 += BATCH) {
        float s8[BATCH];
#pragma unroll
        for (int u = 0; u < BATCH; ++u) {
            float4 t = tile[j0 + u];
            s8[u] = qx * t.x + (qy * t.y + (qz * t.z + t.w));  // dot - rr/2
        }
#pragma unroll
        for (int u = 0; u < BATCH; ++u) {
            bufI[cnt * QPB + tid] = j0 + u;       // unconditional (branchless)
            cnt += (s8[u] > c) ? 1 : 0;
        }
        if (__any(cnt > 8)) { compact(cnt); cnt = 0; }    // cap 16 = 8 + 8
    }
    if (__any(cnt != 0)) compact(cnt);

    // transposed: [b][which][seg][i][N] -> coalesced stores
    const size_t ob = (((size_t)(b * 3 + which) * NSEG + seg) * K_) * N_ + qi;
#pragma unroll
    for (int i = 0; i < K_; ++i) {
        segD[ob + (size_t)i * N_] = __uint_as_float((unsigned)(bd[i] >> 32));
        segI[ob + (size_t)i * N_] = (int)(unsigned)bd[i];
    }
}

__global__ __launch_bounds__(256) void knn_merge_kernel(
    const float* __restrict__ segD, const int* __restrict__ segI,
    int* __restrict__ idxA, int* __restrict__ idxB, int* __restrict__ idxS)
{
    const int b = blockIdx.y, which = blockIdx.z;
    const int qi = blockIdx.x * 256 + threadIdx.x;
    unsigned long long m[K_];
#pragma unroll
    for (int i = 0; i < K_; ++i) m[i] = ~0ull;
    for (int s = 0; s < NSEG; ++s) {
        const size_t ob = (((size_t)(b * 3 + which) * NSEG + s) * K_) * N_ + qi;
        for (int e = 0; e < K_; ++e) {
            unsigned long long key =
                ((unsigned long long)__float_as_uint(segD[ob + (size_t)e * N_]) << 32)
                | (unsigned)segI[ob + (size_t)e * N_];
            if (key >= m[K_ - 1]) break;        // seg list sorted: rest fail too
            m[K_ - 1] = key;
#pragma unroll
            for (int i = K_ - 1; i > 0; --i) {
                if (m[i] < m[i - 1]) {
                    unsigned long long t = m[i]; m[i] = m[i - 1]; m[i - 1] = t;
                }
            }
        }
    }
    int* outp = (which == 0 ? idxA : (which == 1 ? idxB : idxS));
    int* op = outp + ((size_t)b * N_ + qi) * K_;
#pragma unroll
    for (int i = 0; i < K_; ++i) op[i] = (int)(unsigned)m[i];
}

// ----------------------------------------------------- MLP pre-GEMMs -------
__global__ __launch_bounds__(256) void pre_gemm_kernel(
    const float* __restrict__ points1, const float* __restrict__ points2,
    const float* __restrict__ W0,
    float* __restrict__ G1, float* __restrict__ P2)
{
    const int b = blockIdx.y, which = blockIdx.z;
    const float* src = which ? points2 : points1;
    float* dst = which ? P2 : G1;
    const int woff = which ? 64 : 0;
    const int n0 = blockIdx.x * 64;
    const int tid = threadIdx.x;

    __shared__ float sW[64 * 65];   // [c][o]
    __shared__ float sA[64 * 68];   // [c][n] pad 68

    for (int i = tid; i < 4096; i += 256) {
        int c = i & 63, o = i >> 6;
        sW[c * 65 + o] = W0[o * 131 + woff + c];
    }
    for (int i = tid; i < 4096; i += 256) {
        int n = i & 63, c = i >> 6;
        sA[c * 68 + n] = src[((size_t)b * 64 + c) * N_ + n0 + n];
    }
    __syncthreads();

    const int o = tid & 63, qg = tid >> 6;
    float acc[16];
#pragma unroll
    for (int j = 0; j < 16; ++j) acc[j] = 0.f;
    for (int c = 0; c < 64; ++c) {
        float w = sW[c * 65 + o];
        const float4* ap = (const float4*)&sA[c * 68 + qg * 16];
#pragma unroll
        for (int m = 0; m < 4; ++m) {
            float4 a4 = ap[m];
            acc[4 * m + 0] += w * a4.x;
            acc[4 * m + 1] += w * a4.y;
            acc[4 * m + 2] += w * a4.z;
            acc[4 * m + 3] += w * a4.w;
        }
    }
#pragma unroll
    for (int j = 0; j < 16; ++j)
        dst[((size_t)b * N_ + n0 + qg * 16 + j) * 64 + o] = acc[j];
}

// ----------------------------------------------------- MLP main ------------
__global__ __launch_bounds__(256) void mlp2_kernel(
    const float* __restrict__ xyz1, const float* __restrict__ xyz2,
    const float* __restrict__ xyz2w,
    const int* __restrict__ idxA, const int* __restrict__ idxB,
    const float* __restrict__ G1, const float* __restrict__ P2,
    const float* __restrict__ W0, const float* __restrict__ b0,
    const float* __restrict__ W1, const float* __restrict__ b1,
    float* __restrict__ feat, float* __restrict__ featw)
{
    const int b = blockIdx.y, which = blockIdx.z;
    const int* idx = which ? idxB : idxA;
    const float* refxyz = (which ? xyz2w : xyz2) + (size_t)b * 3 * N_;
    float* outp = which ? featw : feat;
    const int n0 = blockIdx.x * 8;
    const int tid = threadIdx.x;
    const int w = tid >> 6, lane = tid & 63;

    __shared__ float sh0[64 * 132];   // [c][row]
    __shared__ float sW1[64 * 68];    // [c][o]
    __shared__ float sWc[3 * 64];
    __shared__ float sB0[64];
    __shared__ float sQ[3][8];
    __shared__ int   sIdx[128];

    for (int i = tid; i < 4096; i += 256) {
        int c = i & 63, o = i >> 6;
        sW1[c * 68 + o] = W1[o * 64 + c];
    }
    if (tid < 192) { int m = tid >> 6, o = tid & 63; sWc[m * 64 + o] = W0[o * 131 + 128 + m]; }
    if (tid < 64) sB0[tid] = b0[tid];
    if (tid < 24) { int m = tid >> 3, j = tid & 7; sQ[m][j] = xyz1[((size_t)b * 3 + m) * N_ + n0 + j]; }
    if (tid < 128) sIdx[tid] = idx[((size_t)b * N_ + n0 + (tid >> 4)) * K_ + (tid & 15)];
    __syncthreads();

    {
        const int o = lane;
        const float wc0 = sWc[o], wc1 = sWc[64 + o], wc2 = sWc[128 + o];
        const float bb0 = sB0[o];
#pragma unroll
        for (int p = 0; p < 2; ++p) {
            const int pl = w * 2 + p;
            const float g1 = G1[((size_t)b * N_ + n0 + pl) * 64 + o];
            const float qx = sQ[0][pl], qy = sQ[1][pl], qz = sQ[2][pl];
            for (int k = 0; k < K_; ++k) {
                const int row = pl * K_ + k;
                const int ii = sIdx[row];
                float p2 = P2[((size_t)b * N_ + ii) * 64 + o];
                float dx = refxyz[ii] - qx;
                float dy = refxyz[N_ + ii] - qy;
                float dz = refxyz[2 * N_ + ii] - qz;
                float h = g1 + p2 + dx * wc0 + dy * wc1 + dz * wc2 + bb0;
                h = h >= 0.f ? h : 0.1f * h;
                sh0[o * 132 + row] = h;
            }
        }
    }
    __syncthreads();

    const int lr = lane >> 3, lo = lane & 7;
    float accv[4][8];
    {
        float4 bva = *(const float4*)&b1[lo * 8];
        float4 bvb = *(const float4*)&b1[lo * 8 + 4];
#pragma unroll
        for (int dr = 0; dr < 4; ++dr) {
            accv[dr][0] = bva.x; accv[dr][1] = bva.y; accv[dr][2] = bva.z; accv[dr][3] = bva.w;
            accv[dr][4] = bvb.x; accv[dr][5] = bvb.y; accv[dr][6] = bvb.z; accv[dr][7] = bvb.w;
        }
    }
    for (int c = 0; c < 64; ++c) {
        float4 a4 = *(const float4*)&sh0[c * 132 + w * 32 + lr * 4];
        float4 wa = *(const float4*)&sW1[c * 68 + lo * 8];
        float4 wb = *(const float4*)&sW1[c * 68 + lo * 8 + 4];
        float av[4] = {a4.x, a4.y, a4.z, a4.w};
        float wv[8] = {wa.x, wa.y, wa.z, wa.w, wb.x, wb.y, wb.z, wb.w};
#pragma unroll
        for (int dr = 0; dr < 4; ++dr)
#pragma unroll
            for (int j = 0; j < 8; ++j)
                accv[dr][j] += av[dr] * wv[j];
    }
#pragma unroll
    for (int dr = 0; dr < 4; ++dr) {
        const int row = w * 32 + lr * 4 + dr;
        const int pl = row >> 4, k = row & 15;
        float o8[8];
#pragma unroll
        for (int j = 0; j < 8; ++j) {
            float v = accv[dr][j];
            o8[j] = v >= 0.f ? v : 0.1f * v;
        }
        float* op = outp + (((size_t)b * N_ + n0 + pl) * K_ + k) * 64 + lo * 8;
        *(float4*)op = make_float4(o8[0], o8[1], o8[2], o8[3]);
        *(float4*)(op + 4) = make_float4(o8[4], o8[5], o8[6], o8[7]);
    }
}

// --------------------------------------------------------------- attn ------
#define NCHUNK 32
#define CG 16
#define NITER ((N_ / NCHUNK) / 16)   // 8

__global__ __launch_bounds__(256) void attn_partial_kernel(
    const float* __restrict__ feat, const float* __restrict__ featw,
    float* __restrict__ partial)
{
    const int chunk = blockIdx.x;
    const int b = blockIdx.y >> 2;
    const int c0 = (blockIdx.y & 3) * CG;
    const int tid = threadIdx.x;
    const int k = tid >> 4, c = tid & 15;

    __shared__ float sf[16 * 16 * 17];
    __shared__ float sfw[16 * 16 * 20];

    float acc[K_];
#pragma unroll
    for (int l = 0; l < K_; ++l) acc[l] = 0.f;

    const int n0 = chunk * (N_ / NCHUNK);
    float rf[16], rfw[16];

    auto LOADG = [&](int ns) {
#pragma unroll
        for (int t = 0; t < 16; ++t) {
            int i = tid + t * 256;
            int nn = i >> 8, p = (i >> 4) & 15, qv = i & 15;
            size_t base = (((size_t)b * N_ + n0 + ns + nn) * K_ + p) * CM_ + c0 + qv;
            rf[t]  = feat[base];
            rfw[t] = featw[base];
        }
    };
    auto STORE = [&]() {
#pragma unroll
        for (int t = 0; t < 16; ++t) {
            int i = tid + t * 256;
            int nn = i >> 8, p = (i >> 4) & 15, qv = i & 15;
            sf[nn * 272 + p * 17 + qv]  = rf[t];
            sfw[nn * 320 + qv * 20 + p] = rfw[t];
        }
    };

    LOADG(0);
    for (int it = 0; it < NITER; ++it) {
        __syncthreads();            // previous compute done (LDS reusable)
        STORE();
        __syncthreads();            // LDS tile ready
        if (it + 1 < NITER) LOADG((it + 1) * 16);   // prefetch under compute
#pragma unroll
        for (int nn = 0; nn < 16; ++nn) {
            float f = sf[nn * 272 + k * 17 + c];
            const float4* fp = (const float4*)&sfw[nn * 320 + c * 20];
#pragma unroll
            for (int m = 0; m < 4; ++m) {
                float4 v = fp[m];
                acc[4 * m + 0] += f * v.x;
                acc[4 * m + 1] += f * v.y;
                acc[4 * m + 2] += f * v.z;
                acc[4 * m + 3] += f * v.w;
            }
        }
    }
    float* pp = partial + ((((size_t)b * NCHUNK + chunk) * CM_ + (c0 + c)) * K_ + k) * K_;
#pragma unroll
    for (int m = 0; m < 4; ++m)
        *(float4*)(pp + 4 * m) = make_float4(acc[4 * m], acc[4 * m + 1], acc[4 * m + 2], acc[4 * m + 3]);
}

__global__ __launch_bounds__(256) void attn_reduce_kernel(
    const float* __restrict__ partial,
    float* __restrict__ rowsum, float* __restrict__ colsum)
{
    const int c = blockIdx.x, b = blockIdx.y;
    const int tid = threadIdx.x;
    const int k = tid >> 4, l = tid & 15;
    __shared__ float smat[K_][K_ + 1];

    float acc = 0.f;
#pragma unroll
    for (int ch = 0; ch < NCHUNK; ++ch)
        acc += partial[((((size_t)b * NCHUNK + ch) * CM_ + c) * K_ + k) * K_ + l];

    float m = acc;
#pragma unroll
    for (int off = 8; off >= 1; off >>= 1) m = fmaxf(m, __shfl_xor(m, off, 16));
    float e = expf(acc - m);
    float s = e;
#pragma unroll
    for (int off = 8; off >= 1; off >>= 1) s += __shfl_xor(s, off, 16);
    float sm = fmaxf((e / s) * 0.57735026918962576f, 1e-10f);

    float rs = sm;
#pragma unroll
    for (int off = 8; off >= 1; off >>= 1) rs += __shfl_xor(rs, off, 16);
    if (l == 0) rowsum[((size_t)b * CM_ + c) * K_ + k] = rs;

    smat[k][l] = sm;
    __syncthreads();
    if (tid < K_) {
        float cs = 0.f;
#pragma unroll
        for (int kk = 0; kk < K_; ++kk) cs += smat[kk][tid];
        colsum[((size_t)b * CM_ + c) * K_ + tid] = cs;
    }
}

// --------------------------------------------------------------- cost ------
__global__ __launch_bounds__(256) void cost_kernel(
    const float* __restrict__ feat, const float* __restrict__ featw,
    const float* __restrict__ rowsum, const float* __restrict__ colsum,
    float* __restrict__ costT, float* __restrict__ costwT)
{
    const int b = blockIdx.y;
    const int tid = threadIdx.x;
    __shared__ float scs[64][K_ + 1], srs[64][K_ + 1];
    for (int i = tid; i < 64 * K_; i += 256) {
        int cc = i >> 4, j = i & 15;
        scs[cc][j] = colsum[((size_t)b * CM_ + cc) * K_ + j];
        srs[cc][j] = rowsum[((size_t)b * CM_ + cc) * K_ + j];
    }
    __syncthreads();
    const int ng = tid >> 6, c = tid & 63;
    const int n = blockIdx.x * 4 + ng;
    const float* fp  = feat  + (((size_t)b * N_ + n) * K_) * 64 + c;
    const float* fwp = featw + (((size_t)b * N_ + n) * K_) * 64 + c;
    float a = 0.f, aw = 0.f;
#pragma unroll
    for (int j = 0; j < K_; ++j) {
        a  += fp[j * 64]  * scs[c][j];
        aw += fwp[j * 64] * srs[c][j];
    }
    costT[((size_t)b * N_ + n) * 64 + c]  = a;
    costwT[((size_t)b * N_ + n) * 64 + c] = aw;
}

// -------------------------------------------------------------- final ------
__global__ __launch_bounds__(256) void final_kernel(
    const float* __restrict__ xyz1,
    const int* __restrict__ idxS,
    const float* __restrict__ costT, const float* __restrict__ costwT,
    const float* __restrict__ wn_W0, const float* __restrict__ wn_b0,
    const float* __restrict__ wn_g0, const float* __restrict__ wn_be0,
    const float* __restrict__ wn_W1, const float* __restrict__ wn_b1,
    const float* __restrict__ wn_g1, const float* __restrict__ wn_be1,
    const float* __restrict__ wn_W2, const float* __restrict__ wn_b2,
    const float* __restrict__ wn_g2, const float* __restrict__ wn_be2,
    float* __restrict__ out)
{
    const int b = blockIdx.y;
    const int tid = threadIdx.x;
    const int ng = tid >> 6, c = tid & 63;
    const int n = blockIdx.x * 4 + ng;
    const float invs = 1.0f / sqrtf(1.0f + 1e-5f);

    __shared__ int   sI[4][K_];
    __shared__ float sH1[4][K_][H_];

    if (c < K_) {
        const int k = c;
        const float* qb = xyz1 + (size_t)b * 3 * N_;
        int ii = idxS[((size_t)b * N_ + n) * K_ + k];
        sI[ng][k] = ii;
        float dx = qb[ii] - qb[n];
        float dy = qb[N_ + ii] - qb[N_ + n];
        float dz = qb[2 * N_ + ii] - qb[2 * N_ + n];
        float h0[H_];
#pragma unroll
        for (int o = 0; o < H_; ++o) {
            float v = wn_W0[o * 3] * dx + wn_W0[o * 3 + 1] * dy + wn_W0[o * 3 + 2] * dz + wn_b0[o];
            v = v * (wn_g0[o] * invs) + wn_be0[o];
            h0[o] = fmaxf(v, 0.f);
        }
#pragma unroll
        for (int o = 0; o < H_; ++o) {
            float v = wn_b1[o];
#pragma unroll
            for (int j = 0; j < H_; ++j) v += wn_W1[o * H_ + j] * h0[j];
            v = v * (wn_g1[o] * invs) + wn_be1[o];
            sH1[ng][k][o] = fmaxf(v, 0.f);
        }
    }
    __syncthreads();

    float w2r[H_];
#pragma unroll
    for (int j = 0; j < H_; ++j) w2r[j] = wn_W2[c * H_ + j];
    const float b2v = wn_b2[c];
    const float s2v = wn_g2[c] * invs;
    const float t2v = wn_be2[c];

    float acc = 0.f;
#pragma unroll
    for (int k = 0; k < K_; ++k) {
        float v = b2v;
#pragma unroll
        for (int j = 0; j < H_; ++j) v += w2r[j] * sH1[ng][k][j];
        float wv = fmaxf(v * s2v + t2v, 0.f);
        int ii = sI[ng][k];
        size_t base = ((size_t)b * N_ + ii) * 64 + c;
        acc += wv * (costT[base] + costwT[base]);
    }
    out[((size_t)b * CM_ + c) * N_ + n] = acc;
}

// ------------------------------------------------------------- launch ------
extern "C" void kernel_launch(void* const* d_in, const int* in_sizes, int n_in,
                              void* d_out, int out_size, void* d_ws, size_t ws_size,
                              hipStream_t stream)
{
    const float* xyz1    = (const float*)d_in[0];
    const float* xyz2    = (const float*)d_in[1];
    const float* xyz2w   = (const float*)d_in[2];
    const float* points1 = (const float*)d_in[3];
    const float* points2 = (const float*)d_in[4];
    const float* mlp_W0  = (const float*)d_in[5];
    const float* mlp_b0  = (const float*)d_in[6];
    const float* mlp_W1  = (const float*)d_in[7];
    const float* mlp_b1  = (const float*)d_in[8];
    const float* wn_W0   = (const float*)d_in[9];
    const float* wn_b0   = (const float*)d_in[10];
    const float* wn_g0   = (const float*)d_in[11];
    const float* wn_be0  = (const float*)d_in[12];
    const float* wn_W1   = (const float*)d_in[13];
    const float* wn_b1   = (const float*)d_in[14];
    const float* wn_g1   = (const float*)d_in[15];
    const float* wn_be1  = (const float*)d_in[16];
    const float* wn_W2   = (const float*)d_in[17];
    const float* wn_b2   = (const float*)d_in[18];
    const float* wn_g2   = (const float*)d_in[19];
    const float* wn_be2  = (const float*)d_in[20];
    float* out = (float*)d_out;

    char* ws = (char*)d_ws;
    size_t off = 0;
    auto alloc = [&](size_t bytes) -> void* {
        void* p = ws + off;
        off += (bytes + 255) & ~(size_t)255;
        return p;
    };
    int*   idxA   = (int*)  alloc((size_t)B_ * N_ * K_ * sizeof(int));
    int*   idxB   = (int*)  alloc((size_t)B_ * N_ * K_ * sizeof(int));
    int*   idxS   = (int*)  alloc((size_t)B_ * N_ * K_ * sizeof(int));
    float* tauBuf = (float*)alloc((size_t)B_ * 3 * N_ * sizeof(float));
    float* feat   = (float*)alloc((size_t)B_ * N_ * K_ * CM_ * sizeof(float));
    float* featw  = (float*)alloc((size_t)B_ * N_ * K_ * CM_ * sizeof(float));
    float* rowsum = (float*)alloc((size_t)B_ * CM_ * K_ * sizeof(float));
    float* colsum = (float*)alloc((size_t)B_ * CM_ * K_ * sizeof(float));
    float* costT  = (float*)alloc((size_t)B_ * N_ * CM_ * sizeof(float));
    float* costwT = (float*)alloc((size_t)B_ * N_ * CM_ * sizeof(float));
    (void)ws_size; (void)in_sizes; (void)n_in; (void)out_size;

    // Aliases, lifetimes chained by stream order (see earlier rounds).
    float* segD    = feat;
    int*   segI    = (int*)featw;
    float* G1      = costT;
    float* P2      = costwT;
    float* partial = costT;   // 4.2 MB spans costT+costwT (both dead then)

    pre_gemm_kernel<<<dim3(N_ / 64, B_, 2), 256, 0, stream>>>(points1, points2, mlp_W0, G1, P2);
    knn_tau_kernel<<<dim3(N_ / QPB, B_, 3), QPB, 0, stream>>>(
        xyz1, xyz2, xyz2w, tauBuf);
    knn_seg_kernel<<<dim3(N_ / QPB, B_, 3 * NSEG), QPB, 0, stream>>>(
        xyz1, xyz2, xyz2w, tauBuf, segD, segI);
    knn_merge_kernel<<<dim3(N_ / 256, B_, 3), 256, 0, stream>>>(
        segD, segI, idxA, idxB, idxS);
    mlp2_kernel<<<dim3(N_ / 8, B_, 2), 256, 0, stream>>>(
        xyz1, xyz2, xyz2w, idxA, idxB, G1, P2,
        mlp_W0, mlp_b0, mlp_W1, mlp_b1, feat, featw);
    attn_partial_kernel<<<dim3(NCHUNK, 4 * B_), 256, 0, stream>>>(feat, featw, partial);
    attn_reduce_kernel<<<dim3(CM_, B_), 256, 0, stream>>>(partial, rowsum, colsum);
    cost_kernel<<<dim3(N_ / 4, B_), 256, 0, stream>>>(feat, featw, rowsum, colsum, costT, costwT);
    final_kernel<<<dim3(N_ / 4, B_), 256, 0, stream>>>(xyz1, idxS, costT, costwT,
                                                       wn_W0, wn_b0, wn_g0, wn_be0,
                                                       wn_W1, wn_b1, wn_g1, wn_be1,
                                                       wn_W2, wn_b2, wn_g2, wn_be2, out);
}